// Round 1
// baseline (3389.001 us; speedup 1.0000x reference)
//
#include <hip/hip_runtime.h>

#define N_NODES 10000
#define F_IN 256
#define HID 512
#define C_OUT 128

// ---------------- zero scratch ----------------
__global__ __launch_bounds__(256) void zero_kernel(float4* __restrict__ p, long long n4) {
    long long i = (long long)blockIdx.x * 256 + threadIdx.x;
    if (i < n4) p[i] = make_float4(0.f, 0.f, 0.f, 0.f);
}

// ---------------- scatter-add: agg[dst[e]] += feat[src[e]] ----------------
// One thread per float4 chunk of one edge. Lanes 0..63 of a wave share an edge
// when chunks>=64 (wave-uniform index loads).
__global__ __launch_bounds__(256)
void scatter_add(const float* __restrict__ feat,
                 const int* __restrict__ src,
                 const int* __restrict__ dst,
                 float* __restrict__ agg,
                 int E, int F, int log2chunks) {
    long long gid = (long long)blockIdx.x * 256 + threadIdx.x;
    int chunks = F >> 2;
    long long e = gid >> log2chunks;
    int c = (int)(gid & (chunks - 1));
    if (e >= E) return;
    int s = src[e];
    int d = dst[e];
    const float4 v = *(const float4*)(feat + (long long)s * F + c * 4);
    float* o = agg + (long long)d * F + c * 4;
    atomicAdd(o + 0, v.x);
    atomicAdd(o + 1, v.y);
    atomicAdd(o + 2, v.z);
    atomicAdd(o + 3, v.w);
}

// ---------------- dual-A GEMM: C = act(A1@B1 + A2@B2 + bias) ----------------
// A1,A2: [M,K] row-major. B1,B2: [K,N] row-major. BM=BN=64, BK=16, 256 thr,
// 4x4 micro-tile per thread. M guarded (clamped loads, predicated stores);
// N assumed multiple of 64, K multiple of 16.
__global__ __launch_bounds__(256)
void dual_gemm(const float* __restrict__ A1, const float* __restrict__ B1, int K1,
               const float* __restrict__ A2, const float* __restrict__ B2, int K2,
               const float* __restrict__ bias,
               float* __restrict__ C, int M, int N, int relu) {
    const int BM = 64, BN = 64, BK = 16;
    __shared__ float As[BK][BM + 4];  // As[k][m]
    __shared__ float Bs[BK][BN + 4];  // Bs[k][n]

    const int t = threadIdx.x;
    const int tx = t & 15;   // 16 col-threads
    const int ty = t >> 4;   // 16 row-threads
    const int row0 = blockIdx.x * BM;
    const int col0 = blockIdx.y * BN;

    // A tile load mapping: thread -> (row = t>>2, kcols = (t&3)*4 .. +3), float4
    const int a_row = t >> 2;
    const int a_col = (t & 3) * 4;
    // B tile load mapping: thread -> (krow = t>>4, cols = (t&15)*4 .. +3), float4
    const int b_row = t >> 4;
    const int b_col = (t & 15) * 4;

    float acc[4][4];
#pragma unroll
    for (int i = 0; i < 4; ++i)
#pragma unroll
        for (int j = 0; j < 4; ++j) acc[i][j] = 0.f;

    for (int seg = 0; seg < 2; ++seg) {
        const float* __restrict__ A = seg ? A2 : A1;
        const float* __restrict__ B = seg ? B2 : B1;
        const int K = seg ? K2 : K1;
        for (int k0 = 0; k0 < K; k0 += BK) {
            // load A tile (clamp row for M boundary; results masked at store)
            int gr = row0 + a_row;
            if (gr >= M) gr = M - 1;
            const float4 av = *(const float4*)(A + (long long)gr * K + k0 + a_col);
            As[a_col + 0][a_row] = av.x;
            As[a_col + 1][a_row] = av.y;
            As[a_col + 2][a_row] = av.z;
            As[a_col + 3][a_row] = av.w;
            // load B tile
            const float4 bv = *(const float4*)(B + (long long)(k0 + b_row) * N + col0 + b_col);
            *(float4*)&Bs[b_row][b_col] = bv;
            __syncthreads();
#pragma unroll
            for (int k = 0; k < BK; ++k) {
                float4 a = *(const float4*)&As[k][ty * 4];
                float4 b = *(const float4*)&Bs[k][tx * 4];
                acc[0][0] += a.x * b.x; acc[0][1] += a.x * b.y; acc[0][2] += a.x * b.z; acc[0][3] += a.x * b.w;
                acc[1][0] += a.y * b.x; acc[1][1] += a.y * b.y; acc[1][2] += a.y * b.z; acc[1][3] += a.y * b.w;
                acc[2][0] += a.z * b.x; acc[2][1] += a.z * b.y; acc[2][2] += a.z * b.z; acc[2][3] += a.z * b.w;
                acc[3][0] += a.w * b.x; acc[3][1] += a.w * b.y; acc[3][2] += a.w * b.z; acc[3][3] += a.w * b.w;
            }
            __syncthreads();
        }
    }

    // epilogue: bias (+ relu), float4 stores
    const int cbase = col0 + tx * 4;
    float4 bi = *(const float4*)(bias + cbase);
#pragma unroll
    for (int i = 0; i < 4; ++i) {
        int r = row0 + ty * 4 + i;
        if (r >= M) continue;
        float4 o;
        o.x = acc[i][0] + bi.x;
        o.y = acc[i][1] + bi.y;
        o.z = acc[i][2] + bi.z;
        o.w = acc[i][3] + bi.w;
        if (relu) {
            o.x = fmaxf(o.x, 0.f); o.y = fmaxf(o.y, 0.f);
            o.z = fmaxf(o.z, 0.f); o.w = fmaxf(o.w, 0.f);
        }
        *(float4*)(C + (long long)r * N + cbase) = o;
    }
}

extern "C" void kernel_launch(void* const* d_in, const int* in_sizes, int n_in,
                              void* d_out, int out_size, void* d_ws, size_t ws_size,
                              hipStream_t stream) {
    const float* x   = (const float*)d_in[0];
    const int*   ei  = (const int*)d_in[1];
    const float* W1l = (const float*)d_in[2];
    const float* b1  = (const float*)d_in[3];
    const float* W1r = (const float*)d_in[4];
    const float* W2l = (const float*)d_in[5];
    const float* b2  = (const float*)d_in[6];
    const float* W2r = (const float*)d_in[7];
    float* out = (float*)d_out;

    const int E = in_sizes[1] / 2;
    const int* src = ei;
    const int* dst = ei + E;

    // workspace layout: agg1 | agg2 | h  (contiguous; agg1+agg2 zeroed together)
    float* agg1 = (float*)d_ws;
    float* agg2 = agg1 + (long long)N_NODES * F_IN;
    float* h    = agg2 + (long long)N_NODES * HID;

    // zero agg1 + agg2 (7.68M floats, contiguous)
    {
        long long n4 = (long long)N_NODES * (F_IN + HID) / 4;
        int blocks = (int)((n4 + 255) / 256);
        zero_kernel<<<blocks, 256, 0, stream>>>((float4*)d_ws, n4);
    }

    // layer 1 aggregate: agg1[dst] += x[src]
    {
        long long work = (long long)E * (F_IN / 4);
        int blocks = (int)((work + 255) / 256);
        scatter_add<<<blocks, 256, 0, stream>>>(x, src, dst, agg1, E, F_IN, 6);
    }

    // h = relu(agg1@W1l + x@W1r + b1)   [10000, 512]
    {
        dim3 grid((N_NODES + 63) / 64, HID / 64);
        dual_gemm<<<grid, 256, 0, stream>>>(agg1, W1l, F_IN, x, W1r, F_IN,
                                            b1, h, N_NODES, HID, 1);
    }

    // layer 2 aggregate: agg2[dst] += h[src]
    {
        long long work = (long long)E * (HID / 4);
        int blocks = (int)((work + 255) / 256);
        scatter_add<<<blocks, 256, 0, stream>>>(h, src, dst, agg2, E, HID, 7);
    }

    // out = agg2@W2l + h@W2r + b2   [10000, 128]
    {
        dim3 grid((N_NODES + 63) / 64, C_OUT / 64);
        dual_gemm<<<grid, 256, 0, stream>>>(agg2, W2l, HID, h, W2r, HID,
                                            b2, out, N_NODES, C_OUT, 0);
    }
}

// Round 2
// 350.367 us; speedup vs baseline: 9.6727x; 9.6727x over previous
//
#include <hip/hip_runtime.h>

#define N_NODES 10000
#define F_IN 256
#define HID 512
#define C_OUT 128
#define NEDGE 320000

// ---------------- zero scratch ----------------
__global__ __launch_bounds__(256) void zero_kernel(int4* __restrict__ p, int n4) {
    int i = blockIdx.x * 256 + threadIdx.x;
    if (i < n4) p[i] = make_int4(0, 0, 0, 0);
}

// ---------------- CSR build ----------------
__global__ __launch_bounds__(256)
void histogram_kernel(const int* __restrict__ dst, int* __restrict__ deg, int E) {
    int e = blockIdx.x * 256 + threadIdx.x;
    if (e < E) atomicAdd(&deg[dst[e]], 1);
}

// single-block exclusive scan of deg[n] -> rowptr[n+1], cursor = rowptr
__global__ __launch_bounds__(256)
void scan_kernel(const int* __restrict__ deg, int* __restrict__ rowptr,
                 int* __restrict__ cursor, int n) {
    __shared__ int sums[256];
    const int t = threadIdx.x;
    const int chunk = (n + 255) / 256;
    const int lo = t * chunk;
    const int hi = min(lo + chunk, n);
    int s = 0;
    for (int i = lo; i < hi; ++i) s += deg[i];
    sums[t] = s;
    __syncthreads();
    // Hillis-Steele inclusive scan
    for (int off = 1; off < 256; off <<= 1) {
        int v = (t >= off) ? sums[t - off] : 0;
        __syncthreads();
        sums[t] += v;
        __syncthreads();
    }
    int run = (t == 0) ? 0 : sums[t - 1];
    for (int i = lo; i < hi; ++i) {
        rowptr[i] = run;
        cursor[i] = run;
        run += deg[i];
    }
    if (t == 255) rowptr[n] = run;
}

__global__ __launch_bounds__(256)
void fill_kernel(const int* __restrict__ src, const int* __restrict__ dst,
                 int* __restrict__ cursor, int* __restrict__ csr_src, int E) {
    int e = blockIdx.x * 256 + threadIdx.x;
    if (e < E) {
        int d = dst[e];
        int pos = atomicAdd(&cursor[d], 1);
        csr_src[pos] = src[e];
    }
}

// ---------------- gather-aggregate: out[n] = sum_{j in row n} feat[csr_src[j]] ----------------
// One wave (64 lanes) per node. F = 64*VW floats per row; lane handles VW floats.
// accum: out[n] += sum (out already holds GEMM result); else out[n] = sum.
template <int VW>
__global__ __launch_bounds__(256)
void gather_aggregate(const float* __restrict__ feat,
                      const int* __restrict__ rowptr,
                      const int* __restrict__ csr_src,
                      float* __restrict__ outp,
                      int nnodes, int accum) {
    const int wid = (blockIdx.x * 256 + threadIdx.x) >> 6;
    if (wid >= nnodes) return;
    const int lane = threadIdx.x & 63;
    const int F = 64 * VW;
    const long long off = (long long)lane * VW;
    const int start = rowptr[wid];
    const int end = rowptr[wid + 1];

    float acc0[VW], acc1[VW];
#pragma unroll
    for (int i = 0; i < VW; ++i) { acc0[i] = 0.f; acc1[i] = 0.f; }

    int j = start;
    for (; j + 1 < end; j += 2) {
        const int s0 = csr_src[j];
        const int s1 = csr_src[j + 1];
        const float* p0 = feat + (long long)s0 * F + off;
        const float* p1 = feat + (long long)s1 * F + off;
#pragma unroll
        for (int i = 0; i < VW; ++i) acc0[i] += p0[i];
#pragma unroll
        for (int i = 0; i < VW; ++i) acc1[i] += p1[i];
    }
    if (j < end) {
        const int s0 = csr_src[j];
        const float* p0 = feat + (long long)s0 * F + off;
#pragma unroll
        for (int i = 0; i < VW; ++i) acc0[i] += p0[i];
    }

    float* o = outp + (long long)wid * F + off;
#pragma unroll
    for (int i = 0; i < VW; ++i) acc0[i] += acc1[i];
    if (accum) {
#pragma unroll
        for (int i = 0; i < VW; ++i) acc0[i] += o[i];
    }
#pragma unroll
    for (int i = 0; i < VW; ++i) o[i] = acc0[i];
}

// ---------------- dual-A GEMM: C = act(A1@B1 + A2@B2 + bias) ----------------
// A1,A2: [M,K] row-major. B1,B2: [K,N] row-major. BM=BN=64, BK=16, 256 thr,
// 4x4 micro-tile per thread. K2 may be 0 (second segment skipped). bias may be null.
__global__ __launch_bounds__(256)
void dual_gemm(const float* __restrict__ A1, const float* __restrict__ B1, int K1,
               const float* __restrict__ A2, const float* __restrict__ B2, int K2,
               const float* __restrict__ bias,
               float* __restrict__ C, int M, int N, int relu) {
    const int BM = 64, BN = 64, BK = 16;
    __shared__ float As[BK][BM + 4];  // As[k][m]
    __shared__ float Bs[BK][BN + 4];  // Bs[k][n]

    const int t = threadIdx.x;
    const int tx = t & 15;
    const int ty = t >> 4;
    const int row0 = blockIdx.x * BM;
    const int col0 = blockIdx.y * BN;

    const int a_row = t >> 2;
    const int a_col = (t & 3) * 4;
    const int b_row = t >> 4;
    const int b_col = (t & 15) * 4;

    float acc[4][4];
#pragma unroll
    for (int i = 0; i < 4; ++i)
#pragma unroll
        for (int j = 0; j < 4; ++j) acc[i][j] = 0.f;

    for (int seg = 0; seg < 2; ++seg) {
        const float* __restrict__ A = seg ? A2 : A1;
        const float* __restrict__ B = seg ? B2 : B1;
        const int K = seg ? K2 : K1;
        for (int k0 = 0; k0 < K; k0 += BK) {
            int gr = row0 + a_row;
            if (gr >= M) gr = M - 1;
            const float4 av = *(const float4*)(A + (long long)gr * K + k0 + a_col);
            As[a_col + 0][a_row] = av.x;
            As[a_col + 1][a_row] = av.y;
            As[a_col + 2][a_row] = av.z;
            As[a_col + 3][a_row] = av.w;
            const float4 bv = *(const float4*)(B + (long long)(k0 + b_row) * N + col0 + b_col);
            *(float4*)&Bs[b_row][b_col] = bv;
            __syncthreads();
#pragma unroll
            for (int k = 0; k < BK; ++k) {
                float4 a = *(const float4*)&As[k][ty * 4];
                float4 b = *(const float4*)&Bs[k][tx * 4];
                acc[0][0] += a.x * b.x; acc[0][1] += a.x * b.y; acc[0][2] += a.x * b.z; acc[0][3] += a.x * b.w;
                acc[1][0] += a.y * b.x; acc[1][1] += a.y * b.y; acc[1][2] += a.y * b.z; acc[1][3] += a.y * b.w;
                acc[2][0] += a.z * b.x; acc[2][1] += a.z * b.y; acc[2][2] += a.z * b.z; acc[2][3] += a.z * b.w;
                acc[3][0] += a.w * b.x; acc[3][1] += a.w * b.y; acc[3][2] += a.w * b.z; acc[3][3] += a.w * b.w;
            }
            __syncthreads();
        }
    }

    const int cbase = col0 + tx * 4;
    float4 bi = bias ? *(const float4*)(bias + cbase) : make_float4(0.f, 0.f, 0.f, 0.f);
#pragma unroll
    for (int i = 0; i < 4; ++i) {
        int r = row0 + ty * 4 + i;
        if (r >= M) continue;
        float4 o;
        o.x = acc[i][0] + bi.x;
        o.y = acc[i][1] + bi.y;
        o.z = acc[i][2] + bi.z;
        o.w = acc[i][3] + bi.w;
        if (relu) {
            o.x = fmaxf(o.x, 0.f); o.y = fmaxf(o.y, 0.f);
            o.z = fmaxf(o.z, 0.f); o.w = fmaxf(o.w, 0.f);
        }
        *(float4*)(C + (long long)r * N + cbase) = o;
    }
}

extern "C" void kernel_launch(void* const* d_in, const int* in_sizes, int n_in,
                              void* d_out, int out_size, void* d_ws, size_t ws_size,
                              hipStream_t stream) {
    const float* x   = (const float*)d_in[0];
    const int*   ei  = (const int*)d_in[1];
    const float* W1l = (const float*)d_in[2];
    const float* b1  = (const float*)d_in[3];
    const float* W1r = (const float*)d_in[4];
    const float* W2l = (const float*)d_in[5];
    const float* b2  = (const float*)d_in[6];
    const float* W2r = (const float*)d_in[7];
    float* out = (float*)d_out;

    const int E = in_sizes[1] / 2;
    const int* src = ei;
    const int* dst = ei + E;

    // ---- workspace layout ----
    char* w = (char*)d_ws;
    int* deg     = (int*)w;                 w += 10016 * sizeof(int);
    int* rowptr  = (int*)w;                 w += 10016 * sizeof(int);
    int* cursor  = (int*)w;                 w += 10016 * sizeof(int);
    int* csr_src = (int*)w;                 w += NEDGE * sizeof(int);
    float* agg1  = (float*)w;               w += (long long)N_NODES * F_IN * sizeof(float);
    float* h     = (float*)w;               w += (long long)N_NODES * HID * sizeof(float);
    float* p     = (float*)w;               w += (long long)N_NODES * C_OUT * sizeof(float);

    // ---- CSR build (by dst) ----
    zero_kernel<<<(10016 / 4 + 255) / 256, 256, 0, stream>>>((int4*)deg, 10016 / 4);
    histogram_kernel<<<(E + 255) / 256, 256, 0, stream>>>(dst, deg, E);
    scan_kernel<<<1, 256, 0, stream>>>(deg, rowptr, cursor, N_NODES);
    fill_kernel<<<(E + 255) / 256, 256, 0, stream>>>(src, dst, cursor, csr_src, E);

    const int agg_blocks = (N_NODES * 64 + 255) / 256;

    // ---- layer 1: agg1 = segsum(x[src]); h = relu(agg1@W1l + x@W1r + b1) ----
    gather_aggregate<4><<<agg_blocks, 256, 0, stream>>>(x, rowptr, csr_src, agg1, N_NODES, 0);
    {
        dim3 grid((N_NODES + 63) / 64, HID / 64);
        dual_gemm<<<grid, 256, 0, stream>>>(agg1, W1l, F_IN, x, W1r, F_IN,
                                            b1, h, N_NODES, HID, 1);
    }

    // ---- layer 2 (swapped): p = h@W2l; out = h@W2r + b2; out += segsum(p[src]) ----
    {
        dim3 grid((N_NODES + 63) / 64, C_OUT / 64);
        dual_gemm<<<grid, 256, 0, stream>>>(h, W2l, HID, h, W2l, 0,
                                            (const float*)nullptr, p, N_NODES, C_OUT, 0);
        dual_gemm<<<grid, 256, 0, stream>>>(h, W2r, HID, h, W2r, 0,
                                            b2, out, N_NODES, C_OUT, 0);
    }
    gather_aggregate<2><<<agg_blocks, 256, 0, stream>>>(p, rowptr, csr_src, out, N_NODES, 1);
}

// Round 3
// 230.490 us; speedup vs baseline: 14.7035x; 1.5201x over previous
//
#include <hip/hip_runtime.h>

#define N_NODES 10000
#define F_IN 256
#define HID 512
#define C_OUT 128
#define NEDGE 320000

typedef __attribute__((ext_vector_type(8))) short short8;
typedef __attribute__((ext_vector_type(4))) float floatx4;

__device__ inline float bf2f_lo(unsigned u) { union { float f; unsigned i; } v; v.i = u << 16; return v.f; }
__device__ inline float bf2f_hi(unsigned u) { union { float f; unsigned i; } v; v.i = u & 0xFFFF0000u; return v.f; }
__device__ inline unsigned short f2bf(float f) {
    union { float f; unsigned i; } v; v.f = f;
    unsigned r = (v.i + 0x7FFFu + ((v.i >> 16) & 1u)) >> 16;
    return (unsigned short)r;
}

// ---------------- zero scratch ----------------
__global__ __launch_bounds__(256) void zero_kernel(int4* __restrict__ p, int n4) {
    int i = blockIdx.x * 256 + threadIdx.x;
    if (i < n4) p[i] = make_int4(0, 0, 0, 0);
}

// ---------------- convert x -> bf16 ----------------
__global__ __launch_bounds__(256)
void convert_x(const float4* __restrict__ xin, uint2* __restrict__ xb, int n4) {
    int i = blockIdx.x * 256 + threadIdx.x;
    if (i >= n4) return;
    float4 v = xin[i];
    uint2 o;
    o.x = (unsigned)f2bf(v.x) | ((unsigned)f2bf(v.y) << 16);
    o.y = (unsigned)f2bf(v.z) | ((unsigned)f2bf(v.w) << 16);
    xb[i] = o;
}

// ---------------- weights: transpose + convert to bf16 [N][K] ----------------
// W1T: [512 n][512 k], k<256 -> W1l[k][n], else W1r[k-256][n]   (W1*: [256][512] row-major)
// W2T: [256 n][512 k], n<128 -> W2l[k][n], else W2r[k][n-128]   (W2*: [512][128] row-major)
__global__ __launch_bounds__(256)
void build_weights(const float* __restrict__ W1l, const float* __restrict__ W1r,
                   const float* __restrict__ W2l, const float* __restrict__ W2r,
                   unsigned short* __restrict__ W1T, unsigned short* __restrict__ W2T) {
    int gid = blockIdx.x * 256 + threadIdx.x;
    if (gid < 512 * 512) {
        int n = gid >> 9, k = gid & 511;
        float v = (k < 256) ? W1l[k * 512 + n] : W1r[(k - 256) * 512 + n];
        W1T[gid] = f2bf(v);
    } else {
        int g = gid - 512 * 512;
        if (g >= 256 * 512) return;
        int n = g >> 9, k = g & 511;
        float v = (n < 128) ? W2l[k * 128 + n] : W2r[k * 128 + (n - 128)];
        W2T[g] = f2bf(v);
    }
}

// ---------------- CSR build ----------------
__global__ __launch_bounds__(256)
void histogram_kernel(const int* __restrict__ dst, int* __restrict__ deg, int E) {
    int e = blockIdx.x * 256 + threadIdx.x;
    if (e < E) atomicAdd(&deg[dst[e]], 1);
}

__global__ __launch_bounds__(256)
void scan_kernel(const int* __restrict__ deg, int* __restrict__ rowptr,
                 int* __restrict__ cursor, int n) {
    __shared__ int sums[256];
    const int t = threadIdx.x;
    const int chunk = (n + 255) / 256;
    const int lo = t * chunk;
    const int hi = min(lo + chunk, n);
    int s = 0;
    for (int i = lo; i < hi; ++i) s += deg[i];
    sums[t] = s;
    __syncthreads();
    for (int off = 1; off < 256; off <<= 1) {
        int v = (t >= off) ? sums[t - off] : 0;
        __syncthreads();
        sums[t] += v;
        __syncthreads();
    }
    int run = (t == 0) ? 0 : sums[t - 1];
    for (int i = lo; i < hi; ++i) {
        rowptr[i] = run;
        cursor[i] = run;
        run += deg[i];
    }
    if (t == 255) rowptr[n] = run;
}

__global__ __launch_bounds__(256)
void fill_kernel(const int* __restrict__ src, const int* __restrict__ dst,
                 int* __restrict__ cursor, int* __restrict__ csr_src, int E) {
    int e = blockIdx.x * 256 + threadIdx.x;
    if (e < E) {
        int d = dst[e];
        int pos = atomicAdd(&cursor[d], 1);
        csr_src[pos] = src[e];
    }
}

// ---------------- gather-aggregate (bf16 feat, F=256): agg[n] = sum feat[src] ----------------
// one wave per node; lane covers 4 bf16 (8 B)
__global__ __launch_bounds__(256)
void gather_agg_256(const unsigned short* __restrict__ feat,
                    const int* __restrict__ rowptr,
                    const int* __restrict__ csr_src,
                    unsigned short* __restrict__ outp, int nnodes) {
    const int wid = (blockIdx.x * 256 + threadIdx.x) >> 6;
    if (wid >= nnodes) return;
    const int lane = threadIdx.x & 63;
    const long long off = (long long)lane * 4;
    const int start = rowptr[wid];
    const int end = rowptr[wid + 1];

    float a0 = 0.f, a1 = 0.f, a2 = 0.f, a3 = 0.f;
    float b0 = 0.f, b1 = 0.f, b2 = 0.f, b3 = 0.f;
    int j = start;
    for (; j + 1 < end; j += 2) {
        const uint2 v0 = *(const uint2*)(feat + (long long)csr_src[j] * 256 + off);
        const uint2 v1 = *(const uint2*)(feat + (long long)csr_src[j + 1] * 256 + off);
        a0 += bf2f_lo(v0.x); a1 += bf2f_hi(v0.x); a2 += bf2f_lo(v0.y); a3 += bf2f_hi(v0.y);
        b0 += bf2f_lo(v1.x); b1 += bf2f_hi(v1.x); b2 += bf2f_lo(v1.y); b3 += bf2f_hi(v1.y);
    }
    if (j < end) {
        const uint2 v0 = *(const uint2*)(feat + (long long)csr_src[j] * 256 + off);
        a0 += bf2f_lo(v0.x); a1 += bf2f_hi(v0.x); a2 += bf2f_lo(v0.y); a3 += bf2f_hi(v0.y);
    }
    a0 += b0; a1 += b1; a2 += b2; a3 += b3;
    uint2 o;
    o.x = (unsigned)f2bf(a0) | ((unsigned)f2bf(a1) << 16);
    o.y = (unsigned)f2bf(a2) | ((unsigned)f2bf(a3) << 16);
    *(uint2*)(outp + (long long)wid * 256 + off) = o;
}

// ---------------- gather-accumulate (bf16 feat, F=128): out[n] += sum feat[src] ----------------
// one wave per node; lane covers 2 bf16 (4 B); out fp32 read-modify-write
__global__ __launch_bounds__(256)
void gather_acc_128(const unsigned short* __restrict__ feat,
                    const int* __restrict__ rowptr,
                    const int* __restrict__ csr_src,
                    float* __restrict__ outp, int nnodes) {
    const int wid = (blockIdx.x * 256 + threadIdx.x) >> 6;
    if (wid >= nnodes) return;
    const int lane = threadIdx.x & 63;
    const long long off = (long long)lane * 2;
    const int start = rowptr[wid];
    const int end = rowptr[wid + 1];

    float a0 = 0.f, a1 = 0.f, b0 = 0.f, b1 = 0.f;
    int j = start;
    for (; j + 1 < end; j += 2) {
        const unsigned v0 = *(const unsigned*)(feat + (long long)csr_src[j] * 128 + off);
        const unsigned v1 = *(const unsigned*)(feat + (long long)csr_src[j + 1] * 128 + off);
        a0 += bf2f_lo(v0); a1 += bf2f_hi(v0);
        b0 += bf2f_lo(v1); b1 += bf2f_hi(v1);
    }
    if (j < end) {
        const unsigned v0 = *(const unsigned*)(feat + (long long)csr_src[j] * 128 + off);
        a0 += bf2f_lo(v0); a1 += bf2f_hi(v0);
    }
    float2* o = (float2*)(outp + (long long)wid * 128 + off);
    float2 cur = *o;
    cur.x += a0 + b0;
    cur.y += a1 + b1;
    *o = cur;
}

// ---------------- MFMA dual-segment GEMM ----------------
// A1[M][K1], A2[M][K2] bf16 row-major; BT[N][K1+K2] bf16 row-major (pre-transposed).
// BM=BN=64, BK=64; 256 thr = 4 waves, each wave 32x32 via 2x2 of 16x16x32 frags.
// MODE 0 (layer1): C0 = h bf16 [M][512], += bias, relu.
// MODE 1 (layer2): cols<128 -> C0 = p bf16 [M][128]; cols>=128 -> C1 = out fp32 [M][128] + bias[col-128].
template <int MODE>
__global__ __launch_bounds__(256)
void mfma_gemm(const unsigned short* __restrict__ A1, int K1,
               const unsigned short* __restrict__ A2, int K2,
               const unsigned short* __restrict__ BT,
               const float* __restrict__ bias,
               void* __restrict__ C0v, void* __restrict__ C1v,
               int M, int Nfull) {
    __shared__ unsigned short A_lds[64][72];
    __shared__ unsigned short B_lds[64][72];

    const int t = threadIdx.x;
    const int lane = t & 63;
    const int w = t >> 6;
    const int wm = w >> 1, wn = w & 1;
    const int l15 = lane & 15;
    const int quad = lane >> 4;
    const int row0 = blockIdx.x * 64;
    const int col0 = blockIdx.y * 64;
    const int Ktot = K1 + K2;

    floatx4 acc00 = {0.f, 0.f, 0.f, 0.f}, acc01 = acc00, acc10 = acc00, acc11 = acc00;

    for (int k0 = 0; k0 < Ktot; k0 += 64) {
        const unsigned short* Ap;
        int astride, acol;
        if (k0 < K1) { Ap = A1; astride = K1; acol = k0; }
        else         { Ap = A2; astride = K2; acol = k0 - K1; }
#pragma unroll
        for (int it = 0; it < 2; ++it) {
            int ch = t + it * 256;
            int row = ch >> 3, c16 = ch & 7;
            int gr = row0 + row; if (gr >= M) gr = M - 1;
            int4 av = *(const int4*)(Ap + (long long)gr * astride + acol + c16 * 8);
            *(int4*)&A_lds[row][c16 * 8] = av;
            int4 bv = *(const int4*)(BT + (long long)(col0 + row) * Ktot + k0 + c16 * 8);
            *(int4*)&B_lds[row][c16 * 8] = bv;
        }
        __syncthreads();
#pragma unroll
        for (int kc = 0; kc < 2; ++kc) {
            short8 a0 = *(short8*)&A_lds[wm * 32 + l15][kc * 32 + quad * 8];
            short8 a1 = *(short8*)&A_lds[wm * 32 + 16 + l15][kc * 32 + quad * 8];
            short8 b0 = *(short8*)&B_lds[wn * 32 + l15][kc * 32 + quad * 8];
            short8 b1 = *(short8*)&B_lds[wn * 32 + 16 + l15][kc * 32 + quad * 8];
            acc00 = __builtin_amdgcn_mfma_f32_16x16x32_bf16(a0, b0, acc00, 0, 0, 0);
            acc01 = __builtin_amdgcn_mfma_f32_16x16x32_bf16(a0, b1, acc01, 0, 0, 0);
            acc10 = __builtin_amdgcn_mfma_f32_16x16x32_bf16(a1, b0, acc10, 0, 0, 0);
            acc11 = __builtin_amdgcn_mfma_f32_16x16x32_bf16(a1, b1, acc11, 0, 0, 0);
        }
        __syncthreads();
    }

    // epilogue: D col = lane&15 (+16j+32wn+col0), row = quad*4+reg (+16i+32wm+row0)
    const int cj0 = col0 + wn * 32 + l15;
    const int cj1 = cj0 + 16;
    const int rbase = row0 + wm * 32 + quad * 4;

    if (MODE == 0) {
        unsigned short* C0 = (unsigned short*)C0v;
        const float bi0 = bias[cj0], bi1 = bias[cj1];
        const floatx4* accs[2][2] = {{&acc00, &acc01}, {&acc10, &acc11}};
#pragma unroll
        for (int i = 0; i < 2; ++i) {
#pragma unroll
            for (int reg = 0; reg < 4; ++reg) {
                int r = rbase + i * 16 + reg;
                if (r >= M) continue;
                float v0 = fmaxf((*accs[i][0])[reg] + bi0, 0.f);
                float v1 = fmaxf((*accs[i][1])[reg] + bi1, 0.f);
                C0[(long long)r * Nfull + cj0] = f2bf(v0);
                C0[(long long)r * Nfull + cj1] = f2bf(v1);
            }
        }
    } else {
        const floatx4* accs[2][2] = {{&acc00, &acc01}, {&acc10, &acc11}};
        if (cj0 < 128) {  // uniform per block (col0 in {0,64})
            unsigned short* C0 = (unsigned short*)C0v;
#pragma unroll
            for (int i = 0; i < 2; ++i) {
#pragma unroll
                for (int reg = 0; reg < 4; ++reg) {
                    int r = rbase + i * 16 + reg;
                    if (r >= M) continue;
                    C0[(long long)r * 128 + cj0] = f2bf((*accs[i][0])[reg]);
                    C0[(long long)r * 128 + cj1] = f2bf((*accs[i][1])[reg]);
                }
            }
        } else {
            float* C1 = (float*)C1v;
            const int d0 = cj0 - 128, d1 = cj1 - 128;
            const float bi0 = bias[d0], bi1 = bias[d1];
#pragma unroll
            for (int i = 0; i < 2; ++i) {
#pragma unroll
                for (int reg = 0; reg < 4; ++reg) {
                    int r = rbase + i * 16 + reg;
                    if (r >= M) continue;
                    C1[(long long)r * 128 + d0] = (*accs[i][0])[reg] + bi0;
                    C1[(long long)r * 128 + d1] = (*accs[i][1])[reg] + bi1;
                }
            }
        }
    }
}

extern "C" void kernel_launch(void* const* d_in, const int* in_sizes, int n_in,
                              void* d_out, int out_size, void* d_ws, size_t ws_size,
                              hipStream_t stream) {
    const float* x   = (const float*)d_in[0];
    const int*   ei  = (const int*)d_in[1];
    const float* W1l = (const float*)d_in[2];
    const float* b1  = (const float*)d_in[3];
    const float* W1r = (const float*)d_in[4];
    const float* W2l = (const float*)d_in[5];
    const float* b2  = (const float*)d_in[6];
    const float* W2r = (const float*)d_in[7];
    float* out = (float*)d_out;

    const int E = in_sizes[1] / 2;
    const int* src = ei;
    const int* dst = ei + E;

    // ---- workspace layout (all 16B aligned) ----
    char* w = (char*)d_ws;
    int* deg     = (int*)w;             w += 10016 * sizeof(int);
    int* rowptr  = (int*)w;             w += 10016 * sizeof(int);
    int* cursor  = (int*)w;             w += 10016 * sizeof(int);
    int* csr_src = (int*)w;             w += NEDGE * sizeof(int);
    unsigned short* xb    = (unsigned short*)w; w += (long long)N_NODES * F_IN * 2;
    unsigned short* agg1b = (unsigned short*)w; w += (long long)N_NODES * F_IN * 2;
    unsigned short* W1T   = (unsigned short*)w; w += 512 * 512 * 2;
    unsigned short* W2T   = (unsigned short*)w; w += 256 * 512 * 2;
    unsigned short* h     = (unsigned short*)w; w += (long long)N_NODES * HID * 2;
    unsigned short* p     = (unsigned short*)w; w += (long long)N_NODES * C_OUT * 2;

    // ---- prep: conversions + CSR build ----
    zero_kernel<<<(10016 / 4 + 255) / 256, 256, 0, stream>>>((int4*)deg, 10016 / 4);
    convert_x<<<(N_NODES * F_IN / 4 + 255) / 256, 256, 0, stream>>>(
        (const float4*)x, (uint2*)xb, N_NODES * F_IN / 4);
    build_weights<<<((512 * 512 + 256 * 512) + 255) / 256, 256, 0, stream>>>(
        W1l, W1r, W2l, W2r, W1T, W2T);
    histogram_kernel<<<(E + 255) / 256, 256, 0, stream>>>(dst, deg, E);
    scan_kernel<<<1, 256, 0, stream>>>(deg, rowptr, cursor, N_NODES);
    fill_kernel<<<(E + 255) / 256, 256, 0, stream>>>(src, dst, cursor, csr_src, E);

    const int agg_blocks = (N_NODES * 64 + 255) / 256;

    // ---- layer 1 ----
    gather_agg_256<<<agg_blocks, 256, 0, stream>>>(xb, rowptr, csr_src, agg1b, N_NODES);
    {
        dim3 grid((N_NODES + 63) / 64, HID / 64);
        mfma_gemm<0><<<grid, 256, 0, stream>>>(agg1b, F_IN, xb, F_IN, W1T, b1,
                                               (void*)h, (void*)nullptr, N_NODES, HID);
    }

    // ---- layer 2 (aggregation swapped past the linear) ----
    {
        dim3 grid((N_NODES + 63) / 64, 256 / 64);
        mfma_gemm<1><<<grid, 256, 0, stream>>>(h, HID, h, 0, W2T, b2,
                                               (void*)p, (void*)out, N_NODES, 256);
    }
    gather_acc_128<<<agg_blocks, 256, 0, stream>>>(p, rowptr, csr_src, out, N_NODES);
}

// Round 4
// 206.835 us; speedup vs baseline: 16.3850x; 1.1144x over previous
//
#include <hip/hip_runtime.h>

#define N_NODES 10000
#define F_IN 256
#define HID 512
#define C_OUT 128
#define NEDGE 320000

typedef __attribute__((ext_vector_type(8))) short short8;
typedef __attribute__((ext_vector_type(4))) float floatx4;

__device__ inline float bf2f_lo(unsigned u) { union { float f; unsigned i; } v; v.i = u << 16; return v.f; }
__device__ inline float bf2f_hi(unsigned u) { union { float f; unsigned i; } v; v.i = u & 0xFFFF0000u; return v.f; }
__device__ inline unsigned short f2bf(float f) {
    union { float f; unsigned i; } v; v.f = f;
    unsigned r = (v.i + 0x7FFFu + ((v.i >> 16) & 1u)) >> 16;
    return (unsigned short)r;
}

// ---------------- fused prep: convert x -> bf16 | transpose weights -> bf16 [N][K] | zero deg ----------------
// blocks [0, 2500): convert_x   (each thread: 4 floats -> 4 bf16)
// blocks [2500, 4036): build_weights (W1T 512x512 then W2T 256x512)
// blocks [4036, 4046): zero deg (int4)
__global__ __launch_bounds__(256)
void prep_kernel(const float4* __restrict__ xin, uint2* __restrict__ xb,
                 const float* __restrict__ W1l, const float* __restrict__ W1r,
                 const float* __restrict__ W2l, const float* __restrict__ W2r,
                 unsigned short* __restrict__ W1T, unsigned short* __restrict__ W2T,
                 int4* __restrict__ deg4) {
    const int b = blockIdx.x;
    if (b < 2500) {
        int i = b * 256 + threadIdx.x;  // < 640000
        float4 v = xin[i];
        uint2 o;
        o.x = (unsigned)f2bf(v.x) | ((unsigned)f2bf(v.y) << 16);
        o.y = (unsigned)f2bf(v.z) | ((unsigned)f2bf(v.w) << 16);
        xb[i] = o;
    } else if (b < 4036) {
        int gid = (b - 2500) * 256 + threadIdx.x;  // < 393216
        if (gid < 512 * 512) {
            int n = gid >> 9, k = gid & 511;
            float v = (k < 256) ? W1l[k * 512 + n] : W1r[(k - 256) * 512 + n];
            W1T[gid] = f2bf(v);
        } else {
            int g = gid - 512 * 512;  // < 131072
            int n = g >> 9, k = g & 511;
            float v = (n < 128) ? W2l[k * 128 + n] : W2r[k * 128 + (n - 128)];
            W2T[g] = f2bf(v);
        }
    } else {
        int i = (b - 4036) * 256 + threadIdx.x;
        if (i < 10016 / 4) deg4[i] = make_int4(0, 0, 0, 0);
    }
}

// ---------------- CSR build ----------------
__global__ __launch_bounds__(256)
void histogram_kernel(const int* __restrict__ dst, int* __restrict__ deg, int E) {
    int e = blockIdx.x * 256 + threadIdx.x;
    if (e < E) atomicAdd(&deg[dst[e]], 1);
}

__global__ __launch_bounds__(256)
void scan_kernel(const int* __restrict__ deg, int* __restrict__ rowptr,
                 int* __restrict__ cursor, int n) {
    __shared__ int sums[256];
    const int t = threadIdx.x;
    const int chunk = (n + 255) / 256;
    const int lo = t * chunk;
    const int hi = min(lo + chunk, n);
    int s = 0;
    for (int i = lo; i < hi; ++i) s += deg[i];
    sums[t] = s;
    __syncthreads();
    for (int off = 1; off < 256; off <<= 1) {
        int v = (t >= off) ? sums[t - off] : 0;
        __syncthreads();
        sums[t] += v;
        __syncthreads();
    }
    int run = (t == 0) ? 0 : sums[t - 1];
    for (int i = lo; i < hi; ++i) {
        rowptr[i] = run;
        cursor[i] = run;
        run += deg[i];
    }
    if (t == 255) rowptr[n] = run;
}

__global__ __launch_bounds__(256)
void fill_kernel(const int* __restrict__ src, const int* __restrict__ dst,
                 int* __restrict__ cursor, int* __restrict__ csr_src, int E) {
    int e = blockIdx.x * 256 + threadIdx.x;
    if (e < E) {
        int d = dst[e];
        int pos = atomicAdd(&cursor[d], 1);
        csr_src[pos] = src[e];
    }
}

// ---------------- gather-aggregate (bf16 feat, F=256): agg[n] = sum feat[src] ----------------
// one wave per node; lane covers 4 bf16 (8B). Unroll-8: batch index load + 8 loads in flight.
__global__ __launch_bounds__(256)
void gather_agg_256(const unsigned short* __restrict__ feat,
                    const int* __restrict__ rowptr,
                    const int* __restrict__ csr_src,
                    unsigned short* __restrict__ outp, int nnodes) {
    const int wid = (blockIdx.x * 256 + threadIdx.x) >> 6;
    if (wid >= nnodes) return;
    const int lane = threadIdx.x & 63;
    const long long off = (long long)lane * 4;
    const int start = __builtin_amdgcn_readfirstlane(rowptr[wid]);
    const int end   = __builtin_amdgcn_readfirstlane(rowptr[wid + 1]);

    float a0[4] = {0.f, 0.f, 0.f, 0.f};
    float a1[4] = {0.f, 0.f, 0.f, 0.f};
    float a2[4] = {0.f, 0.f, 0.f, 0.f};
    float a3[4] = {0.f, 0.f, 0.f, 0.f};

    int j = start;
    for (; j + 8 <= end; j += 8) {
        const int4 ia = *(const int4*)(csr_src + j);
        const int4 ib = *(const int4*)(csr_src + j + 4);
        uint2 v[8];
        v[0] = *(const uint2*)(feat + (long long)ia.x * 256 + off);
        v[1] = *(const uint2*)(feat + (long long)ia.y * 256 + off);
        v[2] = *(const uint2*)(feat + (long long)ia.z * 256 + off);
        v[3] = *(const uint2*)(feat + (long long)ia.w * 256 + off);
        v[4] = *(const uint2*)(feat + (long long)ib.x * 256 + off);
        v[5] = *(const uint2*)(feat + (long long)ib.y * 256 + off);
        v[6] = *(const uint2*)(feat + (long long)ib.z * 256 + off);
        v[7] = *(const uint2*)(feat + (long long)ib.w * 256 + off);
#pragma unroll
        for (int i = 0; i < 8; i += 4) {
            a0[0] += bf2f_lo(v[i].x);     a0[1] += bf2f_hi(v[i].x);     a0[2] += bf2f_lo(v[i].y);     a0[3] += bf2f_hi(v[i].y);
            a1[0] += bf2f_lo(v[i + 1].x); a1[1] += bf2f_hi(v[i + 1].x); a1[2] += bf2f_lo(v[i + 1].y); a1[3] += bf2f_hi(v[i + 1].y);
            a2[0] += bf2f_lo(v[i + 2].x); a2[1] += bf2f_hi(v[i + 2].x); a2[2] += bf2f_lo(v[i + 2].y); a2[3] += bf2f_hi(v[i + 2].y);
            a3[0] += bf2f_lo(v[i + 3].x); a3[1] += bf2f_hi(v[i + 3].x); a3[2] += bf2f_lo(v[i + 3].y); a3[3] += bf2f_hi(v[i + 3].y);
        }
    }
    for (; j < end; ++j) {
        const uint2 v0 = *(const uint2*)(feat + (long long)csr_src[j] * 256 + off);
        a0[0] += bf2f_lo(v0.x); a0[1] += bf2f_hi(v0.x); a0[2] += bf2f_lo(v0.y); a0[3] += bf2f_hi(v0.y);
    }
#pragma unroll
    for (int i = 0; i < 4; ++i) a0[i] += (a1[i] + a2[i]) + a3[i];
    uint2 o;
    o.x = (unsigned)f2bf(a0[0]) | ((unsigned)f2bf(a0[1]) << 16);
    o.y = (unsigned)f2bf(a0[2]) | ((unsigned)f2bf(a0[3]) << 16);
    *(uint2*)(outp + (long long)wid * 256 + off) = o;
}

// ---------------- gather-accumulate (bf16 feat, F=128): out[n] += sum feat[src] ----------------
// one wave per node; lane covers 2 bf16 (4B); out fp32 read-modify-write. Unroll-8.
__global__ __launch_bounds__(256)
void gather_acc_128(const unsigned short* __restrict__ feat,
                    const int* __restrict__ rowptr,
                    const int* __restrict__ csr_src,
                    float* __restrict__ outp, int nnodes) {
    const int wid = (blockIdx.x * 256 + threadIdx.x) >> 6;
    if (wid >= nnodes) return;
    const int lane = threadIdx.x & 63;
    const long long off = (long long)lane * 2;
    const int start = __builtin_amdgcn_readfirstlane(rowptr[wid]);
    const int end   = __builtin_amdgcn_readfirstlane(rowptr[wid + 1]);

    float a0[2] = {0.f, 0.f}, a1[2] = {0.f, 0.f}, a2[2] = {0.f, 0.f}, a3[2] = {0.f, 0.f};

    int j = start;
    for (; j + 8 <= end; j += 8) {
        const int4 ia = *(const int4*)(csr_src + j);
        const int4 ib = *(const int4*)(csr_src + j + 4);
        unsigned v[8];
        v[0] = *(const unsigned*)(feat + (long long)ia.x * 128 + off);
        v[1] = *(const unsigned*)(feat + (long long)ia.y * 128 + off);
        v[2] = *(const unsigned*)(feat + (long long)ia.z * 128 + off);
        v[3] = *(const unsigned*)(feat + (long long)ia.w * 128 + off);
        v[4] = *(const unsigned*)(feat + (long long)ib.x * 128 + off);
        v[5] = *(const unsigned*)(feat + (long long)ib.y * 128 + off);
        v[6] = *(const unsigned*)(feat + (long long)ib.z * 128 + off);
        v[7] = *(const unsigned*)(feat + (long long)ib.w * 128 + off);
#pragma unroll
        for (int i = 0; i < 8; i += 4) {
            a0[0] += bf2f_lo(v[i]);     a0[1] += bf2f_hi(v[i]);
            a1[0] += bf2f_lo(v[i + 1]); a1[1] += bf2f_hi(v[i + 1]);
            a2[0] += bf2f_lo(v[i + 2]); a2[1] += bf2f_hi(v[i + 2]);
            a3[0] += bf2f_lo(v[i + 3]); a3[1] += bf2f_hi(v[i + 3]);
        }
    }
    for (; j < end; ++j) {
        const unsigned v0 = *(const unsigned*)(feat + (long long)csr_src[j] * 128 + off);
        a0[0] += bf2f_lo(v0); a0[1] += bf2f_hi(v0);
    }
    float2* o = (float2*)(outp + (long long)wid * 128 + off);
    float2 cur = *o;
    cur.x += (a0[0] + a1[0]) + (a2[0] + a3[0]);
    cur.y += (a0[1] + a1[1]) + (a2[1] + a3[1]);
    *o = cur;
}

// ---------------- MFMA dual-segment GEMM ----------------
// A1[M][K1], A2[M][K2] bf16 row-major; BT[N][K1+K2] bf16 row-major (pre-transposed).
// BM=BN=64, BK=64; 256 thr = 4 waves, each wave 32x32 via 2x2 of 16x16x32 frags.
// MODE 0 (layer1): C0 = h bf16 [M][512], += bias, relu.
// MODE 1 (layer2): cols<128 -> C0 = p bf16 [M][128]; cols>=128 -> C1 = out fp32 [M][128] + bias[col-128].
template <int MODE>
__global__ __launch_bounds__(256)
void mfma_gemm(const unsigned short* __restrict__ A1, int K1,
               const unsigned short* __restrict__ A2, int K2,
               const unsigned short* __restrict__ BT,
               const float* __restrict__ bias,
               void* __restrict__ C0v, void* __restrict__ C1v,
               int M, int Nfull) {
    __shared__ unsigned short A_lds[64][72];
    __shared__ unsigned short B_lds[64][72];

    const int t = threadIdx.x;
    const int lane = t & 63;
    const int w = t >> 6;
    const int wm = w >> 1, wn = w & 1;
    const int l15 = lane & 15;
    const int quad = lane >> 4;
    const int row0 = blockIdx.x * 64;
    const int col0 = blockIdx.y * 64;
    const int Ktot = K1 + K2;

    floatx4 acc00 = {0.f, 0.f, 0.f, 0.f}, acc01 = acc00, acc10 = acc00, acc11 = acc00;

    for (int k0 = 0; k0 < Ktot; k0 += 64) {
        const unsigned short* Ap;
        int astride, acol;
        if (k0 < K1) { Ap = A1; astride = K1; acol = k0; }
        else         { Ap = A2; astride = K2; acol = k0 - K1; }
#pragma unroll
        for (int it = 0; it < 2; ++it) {
            int ch = t + it * 256;
            int row = ch >> 3, c16 = ch & 7;
            int gr = row0 + row; if (gr >= M) gr = M - 1;
            int4 av = *(const int4*)(Ap + (long long)gr * astride + acol + c16 * 8);
            *(int4*)&A_lds[row][c16 * 8] = av;
            int4 bv = *(const int4*)(BT + (long long)(col0 + row) * Ktot + k0 + c16 * 8);
            *(int4*)&B_lds[row][c16 * 8] = bv;
        }
        __syncthreads();
#pragma unroll
        for (int kc = 0; kc < 2; ++kc) {
            short8 a0 = *(short8*)&A_lds[wm * 32 + l15][kc * 32 + quad * 8];
            short8 a1 = *(short8*)&A_lds[wm * 32 + 16 + l15][kc * 32 + quad * 8];
            short8 b0 = *(short8*)&B_lds[wn * 32 + l15][kc * 32 + quad * 8];
            short8 b1 = *(short8*)&B_lds[wn * 32 + 16 + l15][kc * 32 + quad * 8];
            acc00 = __builtin_amdgcn_mfma_f32_16x16x32_bf16(a0, b0, acc00, 0, 0, 0);
            acc01 = __builtin_amdgcn_mfma_f32_16x16x32_bf16(a0, b1, acc01, 0, 0, 0);
            acc10 = __builtin_amdgcn_mfma_f32_16x16x32_bf16(a1, b0, acc10, 0, 0, 0);
            acc11 = __builtin_amdgcn_mfma_f32_16x16x32_bf16(a1, b1, acc11, 0, 0, 0);
        }
        __syncthreads();
    }

    const int cj0 = col0 + wn * 32 + l15;
    const int cj1 = cj0 + 16;
    const int rbase = row0 + wm * 32 + quad * 4;

    if (MODE == 0) {
        unsigned short* C0 = (unsigned short*)C0v;
        const float bi0 = bias[cj0], bi1 = bias[cj1];
        const floatx4* accs[2][2] = {{&acc00, &acc01}, {&acc10, &acc11}};
#pragma unroll
        for (int i = 0; i < 2; ++i) {
#pragma unroll
            for (int reg = 0; reg < 4; ++reg) {
                int r = rbase + i * 16 + reg;
                if (r >= M) continue;
                float v0 = fmaxf((*accs[i][0])[reg] + bi0, 0.f);
                float v1 = fmaxf((*accs[i][1])[reg] + bi1, 0.f);
                C0[(long long)r * Nfull + cj0] = f2bf(v0);
                C0[(long long)r * Nfull + cj1] = f2bf(v1);
            }
        }
    } else {
        const floatx4* accs[2][2] = {{&acc00, &acc01}, {&acc10, &acc11}};
        if (cj0 < 128) {
            unsigned short* C0 = (unsigned short*)C0v;
#pragma unroll
            for (int i = 0; i < 2; ++i) {
#pragma unroll
                for (int reg = 0; reg < 4; ++reg) {
                    int r = rbase + i * 16 + reg;
                    if (r >= M) continue;
                    C0[(long long)r * 128 + cj0] = f2bf((*accs[i][0])[reg]);
                    C0[(long long)r * 128 + cj1] = f2bf((*accs[i][1])[reg]);
                }
            }
        } else {
            float* C1 = (float*)C1v;
            const int d0 = cj0 - 128, d1 = cj1 - 128;
            const float bi0 = bias[d0], bi1 = bias[d1];
#pragma unroll
            for (int i = 0; i < 2; ++i) {
#pragma unroll
                for (int reg = 0; reg < 4; ++reg) {
                    int r = rbase + i * 16 + reg;
                    if (r >= M) continue;
                    C1[(long long)r * 128 + d0] = (*accs[i][0])[reg] + bi0;
                    C1[(long long)r * 128 + d1] = (*accs[i][1])[reg] + bi1;
                }
            }
        }
    }
}

extern "C" void kernel_launch(void* const* d_in, const int* in_sizes, int n_in,
                              void* d_out, int out_size, void* d_ws, size_t ws_size,
                              hipStream_t stream) {
    const float* x   = (const float*)d_in[0];
    const int*   ei  = (const int*)d_in[1];
    const float* W1l = (const float*)d_in[2];
    const float* b1  = (const float*)d_in[3];
    const float* W1r = (const float*)d_in[4];
    const float* W2l = (const float*)d_in[5];
    const float* b2  = (const float*)d_in[6];
    const float* W2r = (const float*)d_in[7];
    float* out = (float*)d_out;

    const int E = in_sizes[1] / 2;
    const int* src = ei;
    const int* dst = ei + E;

    // ---- workspace layout (all 16B aligned) ----
    char* w = (char*)d_ws;
    int* deg     = (int*)w;             w += 10016 * sizeof(int);
    int* rowptr  = (int*)w;             w += 10016 * sizeof(int);
    int* cursor  = (int*)w;             w += 10016 * sizeof(int);
    int* csr_src = (int*)w;             w += NEDGE * sizeof(int);
    unsigned short* xb    = (unsigned short*)w; w += (long long)N_NODES * F_IN * 2;
    unsigned short* agg1b = (unsigned short*)w; w += (long long)N_NODES * F_IN * 2;
    unsigned short* W1T   = (unsigned short*)w; w += 512 * 512 * 2;
    unsigned short* W2T   = (unsigned short*)w; w += 256 * 512 * 2;
    unsigned short* h     = (unsigned short*)w; w += (long long)N_NODES * HID * 2;
    unsigned short* p     = (unsigned short*)w; w += (long long)N_NODES * C_OUT * 2;

    // ---- prep (fused) + CSR build ----
    prep_kernel<<<4046, 256, 0, stream>>>((const float4*)x, (uint2*)xb,
                                          W1l, W1r, W2l, W2r, W1T, W2T, (int4*)deg);
    histogram_kernel<<<(E + 255) / 256, 256, 0, stream>>>(dst, deg, E);
    scan_kernel<<<1, 256, 0, stream>>>(deg, rowptr, cursor, N_NODES);
    fill_kernel<<<(E + 255) / 256, 256, 0, stream>>>(src, dst, cursor, csr_src, E);

    const int agg_blocks = (N_NODES * 64 + 255) / 256;

    // ---- layer 1 ----
    gather_agg_256<<<agg_blocks, 256, 0, stream>>>(xb, rowptr, csr_src, agg1b, N_NODES);
    {
        dim3 grid((N_NODES + 63) / 64, HID / 64);
        mfma_gemm<0><<<grid, 256, 0, stream>>>(agg1b, F_IN, xb, F_IN, W1T, b1,
                                               (void*)h, (void*)nullptr, N_NODES, HID);
    }

    // ---- layer 2 (aggregation swapped past the linear) ----
    {
        dim3 grid((N_NODES + 63) / 64, 256 / 64);
        mfma_gemm<1><<<grid, 256, 0, stream>>>(h, HID, h, 0, W2T, b2,
                                               (void*)p, (void*)out, N_NODES, 256);
    }
    gather_acc_128<<<agg_blocks, 256, 0, stream>>>(p, rowptr, csr_src, out, N_NODES);
}

// Round 5
// 186.359 us; speedup vs baseline: 18.1853x; 1.1099x over previous
//
#include <hip/hip_runtime.h>

#define N_NODES 10000
#define F_IN 256
#define HID 512
#define C_OUT 128
#define NEDGE 320000

typedef __attribute__((ext_vector_type(8))) short short8;
typedef __attribute__((ext_vector_type(4))) float floatx4;

__device__ inline float bf2f_lo(unsigned u) { union { float f; unsigned i; } v; v.i = u << 16; return v.f; }
__device__ inline float bf2f_hi(unsigned u) { union { float f; unsigned i; } v; v.i = u & 0xFFFF0000u; return v.f; }
__device__ inline unsigned short f2bf(float f) {
    union { float f; unsigned i; } v; v.f = f;
    unsigned r = (v.i + 0x7FFFu + ((v.i >> 16) & 1u)) >> 16;
    return (unsigned short)r;
}
__device__ inline void add8(float* a, uint4 v) {
    a[0] += bf2f_lo(v.x); a[1] += bf2f_hi(v.x);
    a[2] += bf2f_lo(v.y); a[3] += bf2f_hi(v.y);
    a[4] += bf2f_lo(v.z); a[5] += bf2f_hi(v.z);
    a[6] += bf2f_lo(v.w); a[7] += bf2f_hi(v.w);
}

// ---------------- fused prep ----------------
// blocks [0,2500): convert x -> bf16 (float4 coalesced)
// blocks [2500,2756): W1T transpose tiles (32x32, LDS)
// blocks [2756,2884): W2T transpose tiles
// blocks [2884,2894): zero deg
__global__ __launch_bounds__(256)
void prep_kernel(const float4* __restrict__ xin, uint2* __restrict__ xb,
                 const float* __restrict__ W1l, const float* __restrict__ W1r,
                 const float* __restrict__ W2l, const float* __restrict__ W2r,
                 unsigned short* __restrict__ W1T, unsigned short* __restrict__ W2T,
                 int4* __restrict__ deg4) {
    const int b = blockIdx.x;
    const int tid = threadIdx.x;
    if (b < 2500) {
        int i = b * 256 + tid;
        float4 v = xin[i];
        uint2 o;
        o.x = (unsigned)f2bf(v.x) | ((unsigned)f2bf(v.y) << 16);
        o.y = (unsigned)f2bf(v.z) | ((unsigned)f2bf(v.w) << 16);
        xb[i] = o;
        return;
    }
    if (b < 2884) {
        __shared__ float T[32][33];
        const int r = tid >> 3;          // 0..31
        const int c4 = (tid & 7) * 4;    // 0,4,..28
        if (b < 2756) {  // W1T: [512 n][512 k]
            int t = b - 2500;
            int kt = (t & 15) * 32, nt = (t >> 4) * 32;
            int kg = kt + r;
            const float* srcp = (kg < 256) ? (W1l + kg * 512) : (W1r + (kg - 256) * 512);
            float4 v = *(const float4*)(srcp + nt + c4);
            T[c4 + 0][r] = v.x; T[c4 + 1][r] = v.y; T[c4 + 2][r] = v.z; T[c4 + 3][r] = v.w;
            __syncthreads();
            ushort4 o;
            o.x = f2bf(T[r][c4 + 0]); o.y = f2bf(T[r][c4 + 1]);
            o.z = f2bf(T[r][c4 + 2]); o.w = f2bf(T[r][c4 + 3]);
            *(ushort4*)(W1T + (long long)(nt + r) * 512 + kt + c4) = o;
        } else {         // W2T: [256 n][512 k]
            int t = b - 2756;
            int kt = (t & 15) * 32, col0 = (t >> 4) * 32;
            const float* Wsrc; int coloff;
            if (col0 < 128) { Wsrc = W2l; coloff = col0; } else { Wsrc = W2r; coloff = col0 - 128; }
            float4 v = *(const float4*)(Wsrc + (long long)(kt + r) * 128 + coloff + c4);
            T[c4 + 0][r] = v.x; T[c4 + 1][r] = v.y; T[c4 + 2][r] = v.z; T[c4 + 3][r] = v.w;
            __syncthreads();
            ushort4 o;
            o.x = f2bf(T[r][c4 + 0]); o.y = f2bf(T[r][c4 + 1]);
            o.z = f2bf(T[r][c4 + 2]); o.w = f2bf(T[r][c4 + 3]);
            *(ushort4*)(W2T + (long long)(col0 + r) * 512 + kt + c4) = o;
        }
        return;
    }
    {
        int i = (b - 2884) * 256 + tid;
        if (i < 10016 / 4) deg4[i] = make_int4(0, 0, 0, 0);
    }
}

// ---------------- CSR build ----------------
__global__ __launch_bounds__(256)
void histogram_kernel(const int* __restrict__ dst, int* __restrict__ deg, int E) {
    int e = blockIdx.x * 256 + threadIdx.x;
    if (e < E) atomicAdd(&deg[dst[e]], 1);
}

// single block, 1024 threads, 10 elements each; wave-shfl two-level scan
__global__ __launch_bounds__(1024)
void scan_kernel(const int* __restrict__ deg, int* __restrict__ rowptr,
                 int* __restrict__ cursor, int n) {
    const int t = threadIdx.x;
    const int lane = t & 63;
    const int wv = t >> 6;  // 16 waves
    const int lo = t * 10;
    const int hi = min(lo + 10, n);

    int v[10];
#pragma unroll
    for (int i = 0; i < 10; ++i) {
        int idx = lo + i;
        v[i] = (idx < n) ? deg[idx] : 0;
    }
    int s = 0;
#pragma unroll
    for (int i = 0; i < 10; ++i) s += v[i];

    int sc = s;
#pragma unroll
    for (int off = 1; off < 64; off <<= 1) {
        int u = __shfl_up(sc, off, 64);
        if (lane >= off) sc += u;
    }
    __shared__ int wsum[16];
    if (lane == 63) wsum[wv] = sc;
    __syncthreads();
    if (t < 64) {
        int val = (t < 16) ? wsum[t] : 0;
#pragma unroll
        for (int off = 1; off < 16; off <<= 1) {
            int u = __shfl_up(val, off, 64);
            if (t >= off) val += u;
        }
        if (t < 16) wsum[t] = val;
    }
    __syncthreads();
    int waveoff = (wv == 0) ? 0 : wsum[wv - 1];
    int run = waveoff + sc - s;  // exclusive prefix
#pragma unroll
    for (int i = 0; i < 10; ++i) {
        int idx = lo + i;
        if (idx < n) {
            rowptr[idx] = run;
            cursor[idx] = run;
            run += v[i];
        }
    }
    if (lo < n && hi == n) rowptr[n] = run;
}

__global__ __launch_bounds__(256)
void fill_kernel(const int* __restrict__ src, const int* __restrict__ dst,
                 int* __restrict__ cursor, int* __restrict__ csr_src, int E) {
    int e = blockIdx.x * 256 + threadIdx.x;
    if (e < E) {
        int d = dst[e];
        int pos = atomicAdd(&cursor[d], 1);
        csr_src[pos] = src[e];
    }
}

// ---------------- gather-aggregate (bf16, F=256): 2 edges per load instr ----------------
// wave per node; halves (32 lanes x 16B) cover one 512B row each; shfl_xor(32) reduce.
__global__ __launch_bounds__(256)
void gather_agg_256(const unsigned short* __restrict__ feat,
                    const int* __restrict__ rowptr,
                    const int* __restrict__ csr_src,
                    unsigned short* __restrict__ outp, int nnodes) {
    const int wid = (blockIdx.x * 256 + threadIdx.x) >> 6;
    if (wid >= nnodes) return;
    const int lane = threadIdx.x & 63;
    const int half = lane >> 5;
    const int sub = lane & 31;
    const long long myoff = (long long)sub * 8;  // shorts
    const int start = __builtin_amdgcn_readfirstlane(rowptr[wid]);
    const int end   = __builtin_amdgcn_readfirstlane(rowptr[wid + 1]);

    float acc[8] = {0.f, 0.f, 0.f, 0.f, 0.f, 0.f, 0.f, 0.f};
    float accB[8] = {0.f, 0.f, 0.f, 0.f, 0.f, 0.f, 0.f, 0.f};

    int j = start;
    for (; j + 8 <= end; j += 8) {
        int e0 = csr_src[j + 0], e1 = csr_src[j + 1], e2 = csr_src[j + 2], e3 = csr_src[j + 3];
        int e4 = csr_src[j + 4], e5 = csr_src[j + 5], e6 = csr_src[j + 6], e7 = csr_src[j + 7];
        int i0 = half ? e1 : e0;
        int i1 = half ? e3 : e2;
        int i2 = half ? e5 : e4;
        int i3 = half ? e7 : e6;
        uint4 v0 = *(const uint4*)(feat + (long long)i0 * 256 + myoff);
        uint4 v1 = *(const uint4*)(feat + (long long)i1 * 256 + myoff);
        uint4 v2 = *(const uint4*)(feat + (long long)i2 * 256 + myoff);
        uint4 v3 = *(const uint4*)(feat + (long long)i3 * 256 + myoff);
        add8(acc, v0); add8(accB, v1); add8(acc, v2); add8(accB, v3);
    }
    for (; j + 2 <= end; j += 2) {
        int e0 = csr_src[j], e1 = csr_src[j + 1];
        int i0 = half ? e1 : e0;
        uint4 v = *(const uint4*)(feat + (long long)i0 * 256 + myoff);
        add8(acc, v);
    }
    if (j < end) {
        int i0 = csr_src[j];
        uint4 v = *(const uint4*)(feat + (long long)i0 * 256 + myoff);
        if (half == 0) add8(acc, v);
    }
#pragma unroll
    for (int k = 0; k < 8; ++k) acc[k] += accB[k];
#pragma unroll
    for (int k = 0; k < 8; ++k) acc[k] += __shfl_xor(acc[k], 32, 64);

    if (half == 0) {
        uint4 o;
        o.x = (unsigned)f2bf(acc[0]) | ((unsigned)f2bf(acc[1]) << 16);
        o.y = (unsigned)f2bf(acc[2]) | ((unsigned)f2bf(acc[3]) << 16);
        o.z = (unsigned)f2bf(acc[4]) | ((unsigned)f2bf(acc[5]) << 16);
        o.w = (unsigned)f2bf(acc[6]) | ((unsigned)f2bf(acc[7]) << 16);
        *(uint4*)(outp + (long long)wid * 256 + myoff) = o;
    }
}

// ---------------- gather-accumulate (bf16, F=128 -> fp32 out): 4 edges per load instr ----------------
// wave per node; quarters (16 lanes x 16B) cover one 256B row; shfl_xor(16,32) reduce.
__global__ __launch_bounds__(256)
void gather_acc_128(const unsigned short* __restrict__ feat,
                    const int* __restrict__ rowptr,
                    const int* __restrict__ csr_src,
                    float* __restrict__ outp, int nnodes) {
    const int wid = (blockIdx.x * 256 + threadIdx.x) >> 6;
    if (wid >= nnodes) return;
    const int lane = threadIdx.x & 63;
    const int g = lane >> 4;       // 0..3
    const int sub = lane & 15;
    const long long myoff = (long long)sub * 8;  // shorts (16B)
    const int start = __builtin_amdgcn_readfirstlane(rowptr[wid]);
    const int end   = __builtin_amdgcn_readfirstlane(rowptr[wid + 1]);

    // prefetch current out row (lanes < 16): floats [sub*8, sub*8+8)
    float4 c0 = make_float4(0.f, 0.f, 0.f, 0.f), c1 = c0;
    float* orow = outp + (long long)wid * 128 + sub * 8;
    if (lane < 16) {
        c0 = *(const float4*)(orow);
        c1 = *(const float4*)(orow + 4);
    }

    float acc[8] = {0.f, 0.f, 0.f, 0.f, 0.f, 0.f, 0.f, 0.f};
    float accB[8] = {0.f, 0.f, 0.f, 0.f, 0.f, 0.f, 0.f, 0.f};

    int j = start;
    for (; j + 8 <= end; j += 8) {
        int e0 = csr_src[j + 0], e1 = csr_src[j + 1], e2 = csr_src[j + 2], e3 = csr_src[j + 3];
        int e4 = csr_src[j + 4], e5 = csr_src[j + 5], e6 = csr_src[j + 6], e7 = csr_src[j + 7];
        int i0 = (g < 2) ? (g == 0 ? e0 : e1) : (g == 2 ? e2 : e3);
        int i1 = (g < 2) ? (g == 0 ? e4 : e5) : (g == 2 ? e6 : e7);
        uint4 v0 = *(const uint4*)(feat + (long long)i0 * 128 + myoff);
        uint4 v1 = *(const uint4*)(feat + (long long)i1 * 128 + myoff);
        add8(acc, v0); add8(accB, v1);
    }
    for (; j + 4 <= end; j += 4) {
        int e0 = csr_src[j + 0], e1 = csr_src[j + 1], e2 = csr_src[j + 2], e3 = csr_src[j + 3];
        int i0 = (g < 2) ? (g == 0 ? e0 : e1) : (g == 2 ? e2 : e3);
        uint4 v = *(const uint4*)(feat + (long long)i0 * 128 + myoff);
        add8(acc, v);
    }
    int rem = end - j;  // 0..3
    if (rem > 0) {
        int idx = csr_src[j + (g < rem ? g : 0)];
        uint4 v = *(const uint4*)(feat + (long long)idx * 128 + myoff);
        if (g < rem) add8(acc, v);
    }
#pragma unroll
    for (int k = 0; k < 8; ++k) acc[k] += accB[k];
#pragma unroll
    for (int k = 0; k < 8; ++k) acc[k] += __shfl_xor(acc[k], 16, 64);
#pragma unroll
    for (int k = 0; k < 8; ++k) acc[k] += __shfl_xor(acc[k], 32, 64);

    if (lane < 16) {
        c0.x += acc[0]; c0.y += acc[1]; c0.z += acc[2]; c0.w += acc[3];
        c1.x += acc[4]; c1.y += acc[5]; c1.z += acc[6]; c1.w += acc[7];
        *(float4*)(orow) = c0;
        *(float4*)(orow + 4) = c1;
    }
}

// ---------------- MFMA dual-segment GEMM (unchanged) ----------------
template <int MODE>
__global__ __launch_bounds__(256)
void mfma_gemm(const unsigned short* __restrict__ A1, int K1,
               const unsigned short* __restrict__ A2, int K2,
               const unsigned short* __restrict__ BT,
               const float* __restrict__ bias,
               void* __restrict__ C0v, void* __restrict__ C1v,
               int M, int Nfull) {
    __shared__ unsigned short A_lds[64][72];
    __shared__ unsigned short B_lds[64][72];

    const int t = threadIdx.x;
    const int lane = t & 63;
    const int w = t >> 6;
    const int wm = w >> 1, wn = w & 1;
    const int l15 = lane & 15;
    const int quad = lane >> 4;
    const int row0 = blockIdx.x * 64;
    const int col0 = blockIdx.y * 64;
    const int Ktot = K1 + K2;

    floatx4 acc00 = {0.f, 0.f, 0.f, 0.f}, acc01 = acc00, acc10 = acc00, acc11 = acc00;

    for (int k0 = 0; k0 < Ktot; k0 += 64) {
        const unsigned short* Ap;
        int astride, acol;
        if (k0 < K1) { Ap = A1; astride = K1; acol = k0; }
        else         { Ap = A2; astride = K2; acol = k0 - K1; }
#pragma unroll
        for (int it = 0; it < 2; ++it) {
            int ch = t + it * 256;
            int row = ch >> 3, c16 = ch & 7;
            int gr = row0 + row; if (gr >= M) gr = M - 1;
            int4 av = *(const int4*)(Ap + (long long)gr * astride + acol + c16 * 8);
            *(int4*)&A_lds[row][c16 * 8] = av;
            int4 bv = *(const int4*)(BT + (long long)(col0 + row) * Ktot + k0 + c16 * 8);
            *(int4*)&B_lds[row][c16 * 8] = bv;
        }
        __syncthreads();
#pragma unroll
        for (int kc = 0; kc < 2; ++kc) {
            short8 a0 = *(short8*)&A_lds[wm * 32 + l15][kc * 32 + quad * 8];
            short8 a1 = *(short8*)&A_lds[wm * 32 + 16 + l15][kc * 32 + quad * 8];
            short8 b0 = *(short8*)&B_lds[wn * 32 + l15][kc * 32 + quad * 8];
            short8 b1 = *(short8*)&B_lds[wn * 32 + 16 + l15][kc * 32 + quad * 8];
            acc00 = __builtin_amdgcn_mfma_f32_16x16x32_bf16(a0, b0, acc00, 0, 0, 0);
            acc01 = __builtin_amdgcn_mfma_f32_16x16x32_bf16(a0, b1, acc01, 0, 0, 0);
            acc10 = __builtin_amdgcn_mfma_f32_16x16x32_bf16(a1, b0, acc10, 0, 0, 0);
            acc11 = __builtin_amdgcn_mfma_f32_16x16x32_bf16(a1, b1, acc11, 0, 0, 0);
        }
        __syncthreads();
    }

    const int cj0 = col0 + wn * 32 + l15;
    const int cj1 = cj0 + 16;
    const int rbase = row0 + wm * 32 + quad * 4;

    if (MODE == 0) {
        unsigned short* C0 = (unsigned short*)C0v;
        const float bi0 = bias[cj0], bi1 = bias[cj1];
        const floatx4* accs[2][2] = {{&acc00, &acc01}, {&acc10, &acc11}};
#pragma unroll
        for (int i = 0; i < 2; ++i) {
#pragma unroll
            for (int reg = 0; reg < 4; ++reg) {
                int r = rbase + i * 16 + reg;
                if (r >= M) continue;
                float v0 = fmaxf((*accs[i][0])[reg] + bi0, 0.f);
                float v1 = fmaxf((*accs[i][1])[reg] + bi1, 0.f);
                C0[(long long)r * Nfull + cj0] = f2bf(v0);
                C0[(long long)r * Nfull + cj1] = f2bf(v1);
            }
        }
    } else {
        const floatx4* accs[2][2] = {{&acc00, &acc01}, {&acc10, &acc11}};
        if (cj0 < 128) {
            unsigned short* C0 = (unsigned short*)C0v;
#pragma unroll
            for (int i = 0; i < 2; ++i) {
#pragma unroll
                for (int reg = 0; reg < 4; ++reg) {
                    int r = rbase + i * 16 + reg;
                    if (r >= M) continue;
                    C0[(long long)r * 128 + cj0] = f2bf((*accs[i][0])[reg]);
                    C0[(long long)r * 128 + cj1] = f2bf((*accs[i][1])[reg]);
                }
            }
        } else {
            float* C1 = (float*)C1v;
            const int d0 = cj0 - 128, d1 = cj1 - 128;
            const float bi0 = bias[d0], bi1 = bias[d1];
#pragma unroll
            for (int i = 0; i < 2; ++i) {
#pragma unroll
                for (int reg = 0; reg < 4; ++reg) {
                    int r = rbase + i * 16 + reg;
                    if (r >= M) continue;
                    C1[(long long)r * 128 + d0] = (*accs[i][0])[reg] + bi0;
                    C1[(long long)r * 128 + d1] = (*accs[i][1])[reg] + bi1;
                }
            }
        }
    }
}

extern "C" void kernel_launch(void* const* d_in, const int* in_sizes, int n_in,
                              void* d_out, int out_size, void* d_ws, size_t ws_size,
                              hipStream_t stream) {
    const float* x   = (const float*)d_in[0];
    const int*   ei  = (const int*)d_in[1];
    const float* W1l = (const float*)d_in[2];
    const float* b1  = (const float*)d_in[3];
    const float* W1r = (const float*)d_in[4];
    const float* W2l = (const float*)d_in[5];
    const float* b2  = (const float*)d_in[6];
    const float* W2r = (const float*)d_in[7];
    float* out = (float*)d_out;

    const int E = in_sizes[1] / 2;
    const int* src = ei;
    const int* dst = ei + E;

    // ---- workspace layout (all 16B aligned) ----
    char* w = (char*)d_ws;
    int* deg     = (int*)w;             w += 10016 * sizeof(int);
    int* rowptr  = (int*)w;             w += 10016 * sizeof(int);
    int* cursor  = (int*)w;             w += 10016 * sizeof(int);
    int* csr_src = (int*)w;             w += NEDGE * sizeof(int);
    unsigned short* xb    = (unsigned short*)w; w += (long long)N_NODES * F_IN * 2;
    unsigned short* agg1b = (unsigned short*)w; w += (long long)N_NODES * F_IN * 2;
    unsigned short* W1T   = (unsigned short*)w; w += 512 * 512 * 2;
    unsigned short* W2T   = (unsigned short*)w; w += 256 * 512 * 2;
    unsigned short* h     = (unsigned short*)w; w += (long long)N_NODES * HID * 2;
    unsigned short* p     = (unsigned short*)w; w += (long long)N_NODES * C_OUT * 2;

    // ---- prep (fused) + CSR build ----
    prep_kernel<<<2894, 256, 0, stream>>>((const float4*)x, (uint2*)xb,
                                          W1l, W1r, W2l, W2r, W1T, W2T, (int4*)deg);
    histogram_kernel<<<(E + 255) / 256, 256, 0, stream>>>(dst, deg, E);
    scan_kernel<<<1, 1024, 0, stream>>>(deg, rowptr, cursor, N_NODES);
    fill_kernel<<<(E + 255) / 256, 256, 0, stream>>>(src, dst, cursor, csr_src, E);

    const int agg_blocks = (N_NODES * 64 + 255) / 256;

    // ---- layer 1 ----
    gather_agg_256<<<agg_blocks, 256, 0, stream>>>(xb, rowptr, csr_src, agg1b, N_NODES);
    {
        dim3 grid((N_NODES + 63) / 64, HID / 64);
        mfma_gemm<0><<<grid, 256, 0, stream>>>(agg1b, F_IN, xb, F_IN, W1T, b1,
                                               (void*)h, (void*)nullptr, N_NODES, HID);
    }

    // ---- layer 2 (aggregation swapped past the linear) ----
    {
        dim3 grid((N_NODES + 63) / 64, 256 / 64);
        mfma_gemm<1><<<grid, 256, 0, stream>>>(h, HID, h, 0, W2T, b2,
                                               (void*)p, (void*)out, N_NODES, 256);
    }
    gather_acc_128<<<agg_blocks, 256, 0, stream>>>(p, rowptr, csr_src, out, N_NODES);
}

// Round 6
// 161.929 us; speedup vs baseline: 20.9290x; 1.1509x over previous
//
#include <hip/hip_runtime.h>

#define N_NODES 10000
#define F_IN 256
#define HID 512
#define C_OUT 128
#define NEDGE 320000
#define BUCKET 128  // fixed per-node capacity; max degree ~60 for E=320K over N=10K

typedef __attribute__((ext_vector_type(8))) short short8;
typedef __attribute__((ext_vector_type(4))) float floatx4;

__device__ inline float bf2f_lo(unsigned u) { union { float f; unsigned i; } v; v.i = u << 16; return v.f; }
__device__ inline float bf2f_hi(unsigned u) { union { float f; unsigned i; } v; v.i = u & 0xFFFF0000u; return v.f; }
__device__ inline unsigned short f2bf(float f) {
    union { float f; unsigned i; } v; v.f = f;
    unsigned r = (v.i + 0x7FFFu + ((v.i >> 16) & 1u)) >> 16;
    return (unsigned short)r;
}
__device__ inline void add8(float* a, uint4 v) {
    a[0] += bf2f_lo(v.x); a[1] += bf2f_hi(v.x);
    a[2] += bf2f_lo(v.y); a[3] += bf2f_hi(v.y);
    a[4] += bf2f_lo(v.z); a[5] += bf2f_hi(v.z);
    a[6] += bf2f_lo(v.w); a[7] += bf2f_hi(v.w);
}

// ---------------- fused prep ----------------
// blocks [0,2500): convert x -> bf16 (float4 coalesced)
// blocks [2500,2756): W1T transpose tiles (32x32, LDS)
// blocks [2756,2884): W2T transpose tiles
// blocks [2884,2894): zero cursor
__global__ __launch_bounds__(256)
void prep_kernel(const float4* __restrict__ xin, uint2* __restrict__ xb,
                 const float* __restrict__ W1l, const float* __restrict__ W1r,
                 const float* __restrict__ W2l, const float* __restrict__ W2r,
                 unsigned short* __restrict__ W1T, unsigned short* __restrict__ W2T,
                 int4* __restrict__ cursor4) {
    const int b = blockIdx.x;
    const int tid = threadIdx.x;
    if (b < 2500) {
        int i = b * 256 + tid;
        float4 v = xin[i];
        uint2 o;
        o.x = (unsigned)f2bf(v.x) | ((unsigned)f2bf(v.y) << 16);
        o.y = (unsigned)f2bf(v.z) | ((unsigned)f2bf(v.w) << 16);
        xb[i] = o;
        return;
    }
    if (b < 2884) {
        __shared__ float T[32][33];
        const int r = tid >> 3;          // 0..31
        const int c4 = (tid & 7) * 4;    // 0,4,..28
        if (b < 2756) {  // W1T: [512 n][512 k]
            int t = b - 2500;
            int kt = (t & 15) * 32, nt = (t >> 4) * 32;
            int kg = kt + r;
            const float* srcp = (kg < 256) ? (W1l + kg * 512) : (W1r + (kg - 256) * 512);
            float4 v = *(const float4*)(srcp + nt + c4);
            T[c4 + 0][r] = v.x; T[c4 + 1][r] = v.y; T[c4 + 2][r] = v.z; T[c4 + 3][r] = v.w;
            __syncthreads();
            ushort4 o;
            o.x = f2bf(T[r][c4 + 0]); o.y = f2bf(T[r][c4 + 1]);
            o.z = f2bf(T[r][c4 + 2]); o.w = f2bf(T[r][c4 + 3]);
            *(ushort4*)(W1T + (long long)(nt + r) * 512 + kt + c4) = o;
        } else {         // W2T: [256 n][512 k]
            int t = b - 2756;
            int kt = (t & 15) * 32, col0 = (t >> 4) * 32;
            const float* Wsrc; int coloff;
            if (col0 < 128) { Wsrc = W2l; coloff = col0; } else { Wsrc = W2r; coloff = col0 - 128; }
            float4 v = *(const float4*)(Wsrc + (long long)(kt + r) * 128 + coloff + c4);
            T[c4 + 0][r] = v.x; T[c4 + 1][r] = v.y; T[c4 + 2][r] = v.z; T[c4 + 3][r] = v.w;
            __syncthreads();
            ushort4 o;
            o.x = f2bf(T[r][c4 + 0]); o.y = f2bf(T[r][c4 + 1]);
            o.z = f2bf(T[r][c4 + 2]); o.w = f2bf(T[r][c4 + 3]);
            *(ushort4*)(W2T + (long long)(col0 + r) * 512 + kt + c4) = o;
        }
        return;
    }
    {
        int i = (b - 2884) * 256 + tid;
        if (i < (N_NODES + 3) / 4) cursor4[i] = make_int4(0, 0, 0, 0);
    }
}

// ---------------- bucket fill: one atomic pass, no histogram/scan ----------------
__global__ __launch_bounds__(256)
void fill_kernel(const int* __restrict__ src, const int* __restrict__ dst,
                 int* __restrict__ cursor, int* __restrict__ bucket, int E) {
    int e = blockIdx.x * 256 + threadIdx.x;
    if (e < E) {
        int d = dst[e];
        int pos = atomicAdd(&cursor[d], 1);
        bucket[(d << 7) + pos] = src[e];
    }
}

// ---------------- gather-aggregate (bf16, F=256): 2 edges per load instr ----------------
// wave per node; halves (32 lanes x 16B) cover one 512B row each; shfl_xor(32) reduce.
__global__ __launch_bounds__(256)
void gather_agg_256(const unsigned short* __restrict__ feat,
                    const int* __restrict__ cursor,
                    const int* __restrict__ bucket,
                    unsigned short* __restrict__ outp, int nnodes) {
    const int wid = (blockIdx.x * 256 + threadIdx.x) >> 6;
    if (wid >= nnodes) return;
    const int lane = threadIdx.x & 63;
    const int half = lane >> 5;
    const int sub = lane & 31;
    const long long myoff = (long long)sub * 8;  // shorts
    const int cnt = __builtin_amdgcn_readfirstlane(cursor[wid]);
    const int* row = bucket + (wid << 7);

    float acc[8] = {0.f, 0.f, 0.f, 0.f, 0.f, 0.f, 0.f, 0.f};
    float accB[8] = {0.f, 0.f, 0.f, 0.f, 0.f, 0.f, 0.f, 0.f};

    int j = 0;
    for (; j + 8 <= cnt; j += 8) {
        const int4 ia = *(const int4*)(row + j);
        const int4 ib = *(const int4*)(row + j + 4);
        int i0 = half ? ia.y : ia.x;
        int i1 = half ? ia.w : ia.z;
        int i2 = half ? ib.y : ib.x;
        int i3 = half ? ib.w : ib.z;
        uint4 v0 = *(const uint4*)(feat + (long long)i0 * 256 + myoff);
        uint4 v1 = *(const uint4*)(feat + (long long)i1 * 256 + myoff);
        uint4 v2 = *(const uint4*)(feat + (long long)i2 * 256 + myoff);
        uint4 v3 = *(const uint4*)(feat + (long long)i3 * 256 + myoff);
        add8(acc, v0); add8(accB, v1); add8(acc, v2); add8(accB, v3);
    }
    for (; j + 2 <= cnt; j += 2) {
        const int2 e = *(const int2*)(row + j);
        int i0 = half ? e.y : e.x;
        uint4 v = *(const uint4*)(feat + (long long)i0 * 256 + myoff);
        add8(acc, v);
    }
    if (j < cnt) {
        int i0 = row[j];
        uint4 v = *(const uint4*)(feat + (long long)i0 * 256 + myoff);
        if (half == 0) add8(acc, v);
    }
#pragma unroll
    for (int k = 0; k < 8; ++k) acc[k] += accB[k];
#pragma unroll
    for (int k = 0; k < 8; ++k) acc[k] += __shfl_xor(acc[k], 32, 64);

    if (half == 0) {
        uint4 o;
        o.x = (unsigned)f2bf(acc[0]) | ((unsigned)f2bf(acc[1]) << 16);
        o.y = (unsigned)f2bf(acc[2]) | ((unsigned)f2bf(acc[3]) << 16);
        o.z = (unsigned)f2bf(acc[4]) | ((unsigned)f2bf(acc[5]) << 16);
        o.w = (unsigned)f2bf(acc[6]) | ((unsigned)f2bf(acc[7]) << 16);
        *(uint4*)(outp + (long long)wid * 256 + myoff) = o;
    }
}

// ---------------- gather-accumulate (bf16, F=128 -> fp32 out): 4 edges per load instr ----------------
// wave per node; quarters (16 lanes x 16B) cover one 256B row; shfl_xor(16,32) reduce.
__global__ __launch_bounds__(256)
void gather_acc_128(const unsigned short* __restrict__ feat,
                    const int* __restrict__ cursor,
                    const int* __restrict__ bucket,
                    float* __restrict__ outp, int nnodes) {
    const int wid = (blockIdx.x * 256 + threadIdx.x) >> 6;
    if (wid >= nnodes) return;
    const int lane = threadIdx.x & 63;
    const int g = lane >> 4;       // 0..3
    const int sub = lane & 15;
    const long long myoff = (long long)sub * 8;  // shorts (16B)
    const int cnt = __builtin_amdgcn_readfirstlane(cursor[wid]);
    const int* row = bucket + (wid << 7);

    float4 c0 = make_float4(0.f, 0.f, 0.f, 0.f), c1 = c0;
    float* orow = outp + (long long)wid * 128 + sub * 8;
    if (lane < 16) {
        c0 = *(const float4*)(orow);
        c1 = *(const float4*)(orow + 4);
    }

    float acc[8] = {0.f, 0.f, 0.f, 0.f, 0.f, 0.f, 0.f, 0.f};
    float accB[8] = {0.f, 0.f, 0.f, 0.f, 0.f, 0.f, 0.f, 0.f};

    int j = 0;
    for (; j + 8 <= cnt; j += 8) {
        const int4 ia = *(const int4*)(row + j);
        const int4 ib = *(const int4*)(row + j + 4);
        int i0 = (g < 2) ? (g == 0 ? ia.x : ia.y) : (g == 2 ? ia.z : ia.w);
        int i1 = (g < 2) ? (g == 0 ? ib.x : ib.y) : (g == 2 ? ib.z : ib.w);
        uint4 v0 = *(const uint4*)(feat + (long long)i0 * 128 + myoff);
        uint4 v1 = *(const uint4*)(feat + (long long)i1 * 128 + myoff);
        add8(acc, v0); add8(accB, v1);
    }
    for (; j + 4 <= cnt; j += 4) {
        const int4 ia = *(const int4*)(row + j);
        int i0 = (g < 2) ? (g == 0 ? ia.x : ia.y) : (g == 2 ? ia.z : ia.w);
        uint4 v = *(const uint4*)(feat + (long long)i0 * 128 + myoff);
        add8(acc, v);
    }
    int rem = cnt - j;  // 0..3
    if (rem > 0) {
        int idx = row[j + (g < rem ? g : 0)];
        uint4 v = *(const uint4*)(feat + (long long)idx * 128 + myoff);
        if (g < rem) add8(acc, v);
    }
#pragma unroll
    for (int k = 0; k < 8; ++k) acc[k] += accB[k];
#pragma unroll
    for (int k = 0; k < 8; ++k) acc[k] += __shfl_xor(acc[k], 16, 64);
#pragma unroll
    for (int k = 0; k < 8; ++k) acc[k] += __shfl_xor(acc[k], 32, 64);

    if (lane < 16) {
        c0.x += acc[0]; c0.y += acc[1]; c0.z += acc[2]; c0.w += acc[3];
        c1.x += acc[4]; c1.y += acc[5]; c1.z += acc[6]; c1.w += acc[7];
        *(float4*)(orow) = c0;
        *(float4*)(orow + 4) = c1;
    }
}

// ---------------- MFMA dual-segment GEMM (unchanged) ----------------
template <int MODE>
__global__ __launch_bounds__(256)
void mfma_gemm(const unsigned short* __restrict__ A1, int K1,
               const unsigned short* __restrict__ A2, int K2,
               const unsigned short* __restrict__ BT,
               const float* __restrict__ bias,
               void* __restrict__ C0v, void* __restrict__ C1v,
               int M, int Nfull) {
    __shared__ unsigned short A_lds[64][72];
    __shared__ unsigned short B_lds[64][72];

    const int t = threadIdx.x;
    const int lane = t & 63;
    const int w = t >> 6;
    const int wm = w >> 1, wn = w & 1;
    const int l15 = lane & 15;
    const int quad = lane >> 4;
    const int row0 = blockIdx.x * 64;
    const int col0 = blockIdx.y * 64;
    const int Ktot = K1 + K2;

    floatx4 acc00 = {0.f, 0.f, 0.f, 0.f}, acc01 = acc00, acc10 = acc00, acc11 = acc00;

    for (int k0 = 0; k0 < Ktot; k0 += 64) {
        const unsigned short* Ap;
        int astride, acol;
        if (k0 < K1) { Ap = A1; astride = K1; acol = k0; }
        else         { Ap = A2; astride = K2; acol = k0 - K1; }
#pragma unroll
        for (int it = 0; it < 2; ++it) {
            int ch = t + it * 256;
            int row = ch >> 3, c16 = ch & 7;
            int gr = row0 + row; if (gr >= M) gr = M - 1;
            int4 av = *(const int4*)(Ap + (long long)gr * astride + acol + c16 * 8);
            *(int4*)&A_lds[row][c16 * 8] = av;
            int4 bv = *(const int4*)(BT + (long long)(col0 + row) * Ktot + k0 + c16 * 8);
            *(int4*)&B_lds[row][c16 * 8] = bv;
        }
        __syncthreads();
#pragma unroll
        for (int kc = 0; kc < 2; ++kc) {
            short8 a0 = *(short8*)&A_lds[wm * 32 + l15][kc * 32 + quad * 8];
            short8 a1 = *(short8*)&A_lds[wm * 32 + 16 + l15][kc * 32 + quad * 8];
            short8 b0 = *(short8*)&B_lds[wn * 32 + l15][kc * 32 + quad * 8];
            short8 b1 = *(short8*)&B_lds[wn * 32 + 16 + l15][kc * 32 + quad * 8];
            acc00 = __builtin_amdgcn_mfma_f32_16x16x32_bf16(a0, b0, acc00, 0, 0, 0);
            acc01 = __builtin_amdgcn_mfma_f32_16x16x32_bf16(a0, b1, acc01, 0, 0, 0);
            acc10 = __builtin_amdgcn_mfma_f32_16x16x32_bf16(a1, b0, acc10, 0, 0, 0);
            acc11 = __builtin_amdgcn_mfma_f32_16x16x32_bf16(a1, b1, acc11, 0, 0, 0);
        }
        __syncthreads();
    }

    const int cj0 = col0 + wn * 32 + l15;
    const int cj1 = cj0 + 16;
    const int rbase = row0 + wm * 32 + quad * 4;

    if (MODE == 0) {
        unsigned short* C0 = (unsigned short*)C0v;
        const float bi0 = bias[cj0], bi1 = bias[cj1];
        const floatx4* accs[2][2] = {{&acc00, &acc01}, {&acc10, &acc11}};
#pragma unroll
        for (int i = 0; i < 2; ++i) {
#pragma unroll
            for (int reg = 0; reg < 4; ++reg) {
                int r = rbase + i * 16 + reg;
                if (r >= M) continue;
                float v0 = fmaxf((*accs[i][0])[reg] + bi0, 0.f);
                float v1 = fmaxf((*accs[i][1])[reg] + bi1, 0.f);
                C0[(long long)r * Nfull + cj0] = f2bf(v0);
                C0[(long long)r * Nfull + cj1] = f2bf(v1);
            }
        }
    } else {
        const floatx4* accs[2][2] = {{&acc00, &acc01}, {&acc10, &acc11}};
        if (cj0 < 128) {
            unsigned short* C0 = (unsigned short*)C0v;
#pragma unroll
            for (int i = 0; i < 2; ++i) {
#pragma unroll
                for (int reg = 0; reg < 4; ++reg) {
                    int r = rbase + i * 16 + reg;
                    if (r >= M) continue;
                    C0[(long long)r * 128 + cj0] = f2bf((*accs[i][0])[reg]);
                    C0[(long long)r * 128 + cj1] = f2bf((*accs[i][1])[reg]);
                }
            }
        } else {
            float* C1 = (float*)C1v;
            const int d0 = cj0 - 128, d1 = cj1 - 128;
            const float bi0 = bias[d0], bi1 = bias[d1];
#pragma unroll
            for (int i = 0; i < 2; ++i) {
#pragma unroll
                for (int reg = 0; reg < 4; ++reg) {
                    int r = rbase + i * 16 + reg;
                    if (r >= M) continue;
                    C1[(long long)r * 128 + d0] = (*accs[i][0])[reg] + bi0;
                    C1[(long long)r * 128 + d1] = (*accs[i][1])[reg] + bi1;
                }
            }
        }
    }
}

extern "C" void kernel_launch(void* const* d_in, const int* in_sizes, int n_in,
                              void* d_out, int out_size, void* d_ws, size_t ws_size,
                              hipStream_t stream) {
    const float* x   = (const float*)d_in[0];
    const int*   ei  = (const int*)d_in[1];
    const float* W1l = (const float*)d_in[2];
    const float* b1  = (const float*)d_in[3];
    const float* W1r = (const float*)d_in[4];
    const float* W2l = (const float*)d_in[5];
    const float* b2  = (const float*)d_in[6];
    const float* W2r = (const float*)d_in[7];
    float* out = (float*)d_out;

    const int E = in_sizes[1] / 2;
    const int* src = ei;
    const int* dst = ei + E;

    // ---- workspace layout (all 16B aligned) ----
    char* w = (char*)d_ws;
    int* cursor  = (int*)w;             w += 10016 * sizeof(int);
    int* bucket  = (int*)w;             w += (long long)N_NODES * BUCKET * sizeof(int);
    unsigned short* xb    = (unsigned short*)w; w += (long long)N_NODES * F_IN * 2;
    unsigned short* agg1b = (unsigned short*)w; w += (long long)N_NODES * F_IN * 2;
    unsigned short* W1T   = (unsigned short*)w; w += 512 * 512 * 2;
    unsigned short* W2T   = (unsigned short*)w; w += 256 * 512 * 2;
    unsigned short* h     = (unsigned short*)w; w += (long long)N_NODES * HID * 2;
    unsigned short* p     = (unsigned short*)w; w += (long long)N_NODES * C_OUT * 2;

    // ---- prep (convert/transpose/zero-cursor) + bucket fill ----
    prep_kernel<<<2894, 256, 0, stream>>>((const float4*)x, (uint2*)xb,
                                          W1l, W1r, W2l, W2r, W1T, W2T, (int4*)cursor);
    fill_kernel<<<(E + 255) / 256, 256, 0, stream>>>(src, dst, cursor, bucket, E);

    const int agg_blocks = (N_NODES * 64 + 255) / 256;

    // ---- layer 1 ----
    gather_agg_256<<<agg_blocks, 256, 0, stream>>>(xb, cursor, bucket, agg1b, N_NODES);
    {
        dim3 grid((N_NODES + 63) / 64, HID / 64);
        mfma_gemm<0><<<grid, 256, 0, stream>>>(agg1b, F_IN, xb, F_IN, W1T, b1,
                                               (void*)h, (void*)nullptr, N_NODES, HID);
    }

    // ---- layer 2 (aggregation swapped past the linear) ----
    {
        dim3 grid((N_NODES + 63) / 64, 256 / 64);
        mfma_gemm<1><<<grid, 256, 0, stream>>>(h, HID, h, 0, W2T, b2,
                                               (void*)p, (void*)out, N_NODES, 256);
    }
    gather_acc_128<<<agg_blocks, 256, 0, stream>>>(p, cursor, bucket, out, N_NODES);
}

// Round 7
// 161.525 us; speedup vs baseline: 20.9812x; 1.0025x over previous
//
#include <hip/hip_runtime.h>

#define N_NODES 10000
#define F_IN 256
#define HID 512
#define C_OUT 128
#define NEDGE 320000
#define BUCKET 128  // fixed per-node capacity; max degree ~60 for E=320K over N=10K

typedef __attribute__((ext_vector_type(8))) short short8;
typedef __attribute__((ext_vector_type(4))) float floatx4;

__device__ inline float bf2f_lo(unsigned u) { union { float f; unsigned i; } v; v.i = u << 16; return v.f; }
__device__ inline float bf2f_hi(unsigned u) { union { float f; unsigned i; } v; v.i = u & 0xFFFF0000u; return v.f; }
__device__ inline unsigned short f2bf(float f) {
    union { float f; unsigned i; } v; v.f = f;
    unsigned r = (v.i + 0x7FFFu + ((v.i >> 16) & 1u)) >> 16;
    return (unsigned short)r;
}
__device__ inline void add8(float* a, uint4 v) {
    a[0] += bf2f_lo(v.x); a[1] += bf2f_hi(v.x);
    a[2] += bf2f_lo(v.y); a[3] += bf2f_hi(v.y);
    a[4] += bf2f_lo(v.z); a[5] += bf2f_hi(v.z);
    a[6] += bf2f_lo(v.w); a[7] += bf2f_hi(v.w);
}
__device__ inline int sel4(int4 v, int g) {
    return g == 0 ? v.x : (g == 1 ? v.y : (g == 2 ? v.z : v.w));
}

// ---------------- fused prep ----------------
__global__ __launch_bounds__(256)
void prep_kernel(const float4* __restrict__ xin, uint2* __restrict__ xb,
                 const float* __restrict__ W1l, const float* __restrict__ W1r,
                 const float* __restrict__ W2l, const float* __restrict__ W2r,
                 unsigned short* __restrict__ W1T, unsigned short* __restrict__ W2T,
                 int4* __restrict__ cursor4) {
    const int b = blockIdx.x;
    const int tid = threadIdx.x;
    if (b < 2500) {
        int i = b * 256 + tid;
        float4 v = xin[i];
        uint2 o;
        o.x = (unsigned)f2bf(v.x) | ((unsigned)f2bf(v.y) << 16);
        o.y = (unsigned)f2bf(v.z) | ((unsigned)f2bf(v.w) << 16);
        xb[i] = o;
        return;
    }
    if (b < 2884) {
        __shared__ float T[32][33];
        const int r = tid >> 3;          // 0..31
        const int c4 = (tid & 7) * 4;    // 0,4,..28
        if (b < 2756) {  // W1T: [512 n][512 k]
            int t = b - 2500;
            int kt = (t & 15) * 32, nt = (t >> 4) * 32;
            int kg = kt + r;
            const float* srcp = (kg < 256) ? (W1l + kg * 512) : (W1r + (kg - 256) * 512);
            float4 v = *(const float4*)(srcp + nt + c4);
            T[c4 + 0][r] = v.x; T[c4 + 1][r] = v.y; T[c4 + 2][r] = v.z; T[c4 + 3][r] = v.w;
            __syncthreads();
            ushort4 o;
            o.x = f2bf(T[r][c4 + 0]); o.y = f2bf(T[r][c4 + 1]);
            o.z = f2bf(T[r][c4 + 2]); o.w = f2bf(T[r][c4 + 3]);
            *(ushort4*)(W1T + (long long)(nt + r) * 512 + kt + c4) = o;
        } else {         // W2T: [256 n][512 k]
            int t = b - 2756;
            int kt = (t & 15) * 32, col0 = (t >> 4) * 32;
            const float* Wsrc; int coloff;
            if (col0 < 128) { Wsrc = W2l; coloff = col0; } else { Wsrc = W2r; coloff = col0 - 128; }
            float4 v = *(const float4*)(Wsrc + (long long)(kt + r) * 128 + coloff + c4);
            T[c4 + 0][r] = v.x; T[c4 + 1][r] = v.y; T[c4 + 2][r] = v.z; T[c4 + 3][r] = v.w;
            __syncthreads();
            ushort4 o;
            o.x = f2bf(T[r][c4 + 0]); o.y = f2bf(T[r][c4 + 1]);
            o.z = f2bf(T[r][c4 + 2]); o.w = f2bf(T[r][c4 + 3]);
            *(ushort4*)(W2T + (long long)(col0 + r) * 512 + kt + c4) = o;
        }
        return;
    }
    {
        int i = (b - 2884) * 256 + tid;
        if (i < (N_NODES + 3) / 4) cursor4[i] = make_int4(0, 0, 0, 0);
    }
}

// ---------------- bucket fill: one atomic pass ----------------
__global__ __launch_bounds__(256)
void fill_kernel(const int* __restrict__ src, const int* __restrict__ dst,
                 int* __restrict__ cursor, int* __restrict__ bucket, int E) {
    int e = blockIdx.x * 256 + threadIdx.x;
    if (e < E) {
        int d = dst[e];
        int pos = atomicAdd(&cursor[d], 1);
        bucket[(d << 7) + pos] = src[e];
    }
}

// ---------------- gather-aggregate (bf16, F=256), unroll-16: 8 loads in flight ----------------
__global__ __launch_bounds__(256)
void gather_agg_256(const unsigned short* __restrict__ feat,
                    const int* __restrict__ cursor,
                    const int* __restrict__ bucket,
                    unsigned short* __restrict__ outp, int nnodes) {
    const int wid = (blockIdx.x * 256 + threadIdx.x) >> 6;
    if (wid >= nnodes) return;
    const int lane = threadIdx.x & 63;
    const int half = lane >> 5;
    const int sub = lane & 31;
    const long long myoff = (long long)sub * 8;  // shorts
    const int cnt = __builtin_amdgcn_readfirstlane(cursor[wid]);
    const int* row = bucket + (wid << 7);

    float acc[8] = {0.f, 0.f, 0.f, 0.f, 0.f, 0.f, 0.f, 0.f};
    float accB[8] = {0.f, 0.f, 0.f, 0.f, 0.f, 0.f, 0.f, 0.f};

    int j = 0;
    for (; j + 16 <= cnt; j += 16) {
        const int4 ia = *(const int4*)(row + j);
        const int4 ib = *(const int4*)(row + j + 4);
        const int4 ic = *(const int4*)(row + j + 8);
        const int4 id = *(const int4*)(row + j + 12);
        int i0 = half ? ia.y : ia.x;
        int i1 = half ? ia.w : ia.z;
        int i2 = half ? ib.y : ib.x;
        int i3 = half ? ib.w : ib.z;
        int i4 = half ? ic.y : ic.x;
        int i5 = half ? ic.w : ic.z;
        int i6 = half ? id.y : id.x;
        int i7 = half ? id.w : id.z;
        uint4 v0 = *(const uint4*)(feat + (long long)i0 * 256 + myoff);
        uint4 v1 = *(const uint4*)(feat + (long long)i1 * 256 + myoff);
        uint4 v2 = *(const uint4*)(feat + (long long)i2 * 256 + myoff);
        uint4 v3 = *(const uint4*)(feat + (long long)i3 * 256 + myoff);
        uint4 v4 = *(const uint4*)(feat + (long long)i4 * 256 + myoff);
        uint4 v5 = *(const uint4*)(feat + (long long)i5 * 256 + myoff);
        uint4 v6 = *(const uint4*)(feat + (long long)i6 * 256 + myoff);
        uint4 v7 = *(const uint4*)(feat + (long long)i7 * 256 + myoff);
        add8(acc, v0); add8(accB, v1); add8(acc, v2); add8(accB, v3);
        add8(acc, v4); add8(accB, v5); add8(acc, v6); add8(accB, v7);
    }
    for (; j + 8 <= cnt; j += 8) {
        const int4 ia = *(const int4*)(row + j);
        const int4 ib = *(const int4*)(row + j + 4);
        int i0 = half ? ia.y : ia.x;
        int i1 = half ? ia.w : ia.z;
        int i2 = half ? ib.y : ib.x;
        int i3 = half ? ib.w : ib.z;
        uint4 v0 = *(const uint4*)(feat + (long long)i0 * 256 + myoff);
        uint4 v1 = *(const uint4*)(feat + (long long)i1 * 256 + myoff);
        uint4 v2 = *(const uint4*)(feat + (long long)i2 * 256 + myoff);
        uint4 v3 = *(const uint4*)(feat + (long long)i3 * 256 + myoff);
        add8(acc, v0); add8(accB, v1); add8(acc, v2); add8(accB, v3);
    }
    for (; j + 2 <= cnt; j += 2) {
        const int2 e = *(const int2*)(row + j);
        int i0 = half ? e.y : e.x;
        uint4 v = *(const uint4*)(feat + (long long)i0 * 256 + myoff);
        add8(acc, v);
    }
    if (j < cnt) {
        int i0 = row[j];
        uint4 v = *(const uint4*)(feat + (long long)i0 * 256 + myoff);
        if (half == 0) add8(acc, v);
    }
#pragma unroll
    for (int k = 0; k < 8; ++k) acc[k] += accB[k];
#pragma unroll
    for (int k = 0; k < 8; ++k) acc[k] += __shfl_xor(acc[k], 32, 64);

    if (half == 0) {
        uint4 o;
        o.x = (unsigned)f2bf(acc[0]) | ((unsigned)f2bf(acc[1]) << 16);
        o.y = (unsigned)f2bf(acc[2]) | ((unsigned)f2bf(acc[3]) << 16);
        o.z = (unsigned)f2bf(acc[4]) | ((unsigned)f2bf(acc[5]) << 16);
        o.w = (unsigned)f2bf(acc[6]) | ((unsigned)f2bf(acc[7]) << 16);
        *(uint4*)(outp + (long long)wid * 256 + myoff) = o;
    }
}

// ---------------- gather-accumulate (bf16, F=128 -> fp32 out), unroll-16: 4 loads in flight ----------------
__global__ __launch_bounds__(256)
void gather_acc_128(const unsigned short* __restrict__ feat,
                    const int* __restrict__ cursor,
                    const int* __restrict__ bucket,
                    float* __restrict__ outp, int nnodes) {
    const int wid = (blockIdx.x * 256 + threadIdx.x) >> 6;
    if (wid >= nnodes) return;
    const int lane = threadIdx.x & 63;
    const int g = lane >> 4;       // 0..3
    const int sub = lane & 15;
    const long long myoff = (long long)sub * 8;  // shorts (16B)
    const int cnt = __builtin_amdgcn_readfirstlane(cursor[wid]);
    const int* row = bucket + (wid << 7);

    float4 c0 = make_float4(0.f, 0.f, 0.f, 0.f), c1 = c0;
    float* orow = outp + (long long)wid * 128 + sub * 8;
    if (lane < 16) {
        c0 = *(const float4*)(orow);
        c1 = *(const float4*)(orow + 4);
    }

    float acc[8] = {0.f, 0.f, 0.f, 0.f, 0.f, 0.f, 0.f, 0.f};
    float accB[8] = {0.f, 0.f, 0.f, 0.f, 0.f, 0.f, 0.f, 0.f};

    int j = 0;
    for (; j + 16 <= cnt; j += 16) {
        const int4 ia = *(const int4*)(row + j);
        const int4 ib = *(const int4*)(row + j + 4);
        const int4 ic = *(const int4*)(row + j + 8);
        const int4 id = *(const int4*)(row + j + 12);
        int i0 = sel4(ia, g), i1 = sel4(ib, g), i2 = sel4(ic, g), i3 = sel4(id, g);
        uint4 v0 = *(const uint4*)(feat + (long long)i0 * 128 + myoff);
        uint4 v1 = *(const uint4*)(feat + (long long)i1 * 128 + myoff);
        uint4 v2 = *(const uint4*)(feat + (long long)i2 * 128 + myoff);
        uint4 v3 = *(const uint4*)(feat + (long long)i3 * 128 + myoff);
        add8(acc, v0); add8(accB, v1); add8(acc, v2); add8(accB, v3);
    }
    for (; j + 8 <= cnt; j += 8) {
        const int4 ia = *(const int4*)(row + j);
        const int4 ib = *(const int4*)(row + j + 4);
        int i0 = sel4(ia, g), i1 = sel4(ib, g);
        uint4 v0 = *(const uint4*)(feat + (long long)i0 * 128 + myoff);
        uint4 v1 = *(const uint4*)(feat + (long long)i1 * 128 + myoff);
        add8(acc, v0); add8(accB, v1);
    }
    for (; j + 4 <= cnt; j += 4) {
        const int4 ia = *(const int4*)(row + j);
        int i0 = sel4(ia, g);
        uint4 v = *(const uint4*)(feat + (long long)i0 * 128 + myoff);
        add8(acc, v);
    }
    int rem = cnt - j;  // 0..3
    if (rem > 0) {
        int idx = row[j + (g < rem ? g : 0)];
        uint4 v = *(const uint4*)(feat + (long long)idx * 128 + myoff);
        if (g < rem) add8(acc, v);
    }
#pragma unroll
    for (int k = 0; k < 8; ++k) acc[k] += accB[k];
#pragma unroll
    for (int k = 0; k < 8; ++k) acc[k] += __shfl_xor(acc[k], 16, 64);
#pragma unroll
    for (int k = 0; k < 8; ++k) acc[k] += __shfl_xor(acc[k], 32, 64);

    if (lane < 16) {
        c0.x += acc[0]; c0.y += acc[1]; c0.z += acc[2]; c0.w += acc[3];
        c1.x += acc[4]; c1.y += acc[5]; c1.z += acc[6]; c1.w += acc[7];
        *(float4*)(orow) = c0;
        *(float4*)(orow + 4) = c1;
    }
}

// ---------------- MFMA dual-segment GEMM: BM=128, BN=64, BK=64 ----------------
// 4 waves; wave w owns rows [w*32, w*32+32) x all 64 cols: 2 row-frags x 4 col-frags.
// MODE 0: C0 = relu(acc + bias) -> h bf16 [M][Nfull]
// MODE 1: cols<128 -> C0 = p bf16 [M][128]; cols>=128 -> C1 = out fp32 [M][128] + bias
template <int MODE>
__global__ __launch_bounds__(256)
void mfma_gemm(const unsigned short* __restrict__ A1, int K1,
               const unsigned short* __restrict__ A2, int K2,
               const unsigned short* __restrict__ BT,
               const float* __restrict__ bias,
               void* __restrict__ C0v, void* __restrict__ C1v,
               int M, int Nfull) {
    __shared__ unsigned short A_lds[128][72];
    __shared__ unsigned short B_lds[64][72];

    const int t = threadIdx.x;
    const int lane = t & 63;
    const int w = t >> 6;       // wave row-group 0..3
    const int l15 = lane & 15;
    const int quad = lane >> 4;
    const int row0 = blockIdx.x * 128;
    const int col0 = blockIdx.y * 64;
    const int Ktot = K1 + K2;

    floatx4 acc[2][4];
#pragma unroll
    for (int i = 0; i < 2; ++i)
#pragma unroll
        for (int cf = 0; cf < 4; ++cf) acc[i][cf] = (floatx4){0.f, 0.f, 0.f, 0.f};

    const int srow = t >> 3;        // 0..31
    const int scol = (t & 7) * 8;   // shorts

    for (int k0 = 0; k0 < Ktot; k0 += 64) {
        const unsigned short* Ap;
        int astride, acol;
        if (k0 < K1) { Ap = A1; astride = K1; acol = k0; }
        else         { Ap = A2; astride = K2; acol = k0 - K1; }
#pragma unroll
        for (int it = 0; it < 4; ++it) {
            int row = srow + it * 32;
            int gr = row0 + row; if (gr >= M) gr = M - 1;
            *(int4*)&A_lds[row][scol] = *(const int4*)(Ap + (long long)gr * astride + acol + scol);
        }
#pragma unroll
        for (int it = 0; it < 2; ++it) {
            int row = srow + it * 32;
            *(int4*)&B_lds[row][scol] = *(const int4*)(BT + (long long)(col0 + row) * Ktot + k0 + scol);
        }
        __syncthreads();
#pragma unroll
        for (int kc = 0; kc < 2; ++kc) {
            short8 a0 = *(short8*)&A_lds[w * 32 + l15][kc * 32 + quad * 8];
            short8 a1 = *(short8*)&A_lds[w * 32 + 16 + l15][kc * 32 + quad * 8];
            short8 bb[4];
#pragma unroll
            for (int cf = 0; cf < 4; ++cf)
                bb[cf] = *(short8*)&B_lds[cf * 16 + l15][kc * 32 + quad * 8];
#pragma unroll
            for (int cf = 0; cf < 4; ++cf) {
                acc[0][cf] = __builtin_amdgcn_mfma_f32_16x16x32_bf16(a0, bb[cf], acc[0][cf], 0, 0, 0);
                acc[1][cf] = __builtin_amdgcn_mfma_f32_16x16x32_bf16(a1, bb[cf], acc[1][cf], 0, 0, 0);
            }
        }
        __syncthreads();
    }

    // epilogue: row = row0 + w*32 + i*16 + quad*4 + reg; col = col0 + cf*16 + l15
    const int rbase = row0 + w * 32 + quad * 4;

    if (MODE == 0) {
        unsigned short* C0 = (unsigned short*)C0v;
#pragma unroll
        for (int cf = 0; cf < 4; ++cf) {
            const int cj = col0 + cf * 16 + l15;
            const float bi = bias[cj];
#pragma unroll
            for (int i = 0; i < 2; ++i) {
#pragma unroll
                for (int reg = 0; reg < 4; ++reg) {
                    int r = rbase + i * 16 + reg;
                    if (r >= M) continue;
                    C0[(long long)r * Nfull + cj] = f2bf(fmaxf(acc[i][cf][reg] + bi, 0.f));
                }
            }
        }
    } else {
        if (col0 < 128) {
            unsigned short* C0 = (unsigned short*)C0v;
#pragma unroll
            for (int cf = 0; cf < 4; ++cf) {
                const int cj = col0 + cf * 16 + l15;
#pragma unroll
                for (int i = 0; i < 2; ++i) {
#pragma unroll
                    for (int reg = 0; reg < 4; ++reg) {
                        int r = rbase + i * 16 + reg;
                        if (r >= M) continue;
                        C0[(long long)r * 128 + cj] = f2bf(acc[i][cf][reg]);
                    }
                }
            }
        } else {
            float* C1 = (float*)C1v;
#pragma unroll
            for (int cf = 0; cf < 4; ++cf) {
                const int d = col0 - 128 + cf * 16 + l15;
                const float bi = bias[d];
#pragma unroll
                for (int i = 0; i < 2; ++i) {
#pragma unroll
                    for (int reg = 0; reg < 4; ++reg) {
                        int r = rbase + i * 16 + reg;
                        if (r >= M) continue;
                        C1[(long long)r * 128 + d] = acc[i][cf][reg] + bi;
                    }
                }
            }
        }
    }
}

extern "C" void kernel_launch(void* const* d_in, const int* in_sizes, int n_in,
                              void* d_out, int out_size, void* d_ws, size_t ws_size,
                              hipStream_t stream) {
    const float* x   = (const float*)d_in[0];
    const int*   ei  = (const int*)d_in[1];
    const float* W1l = (const float*)d_in[2];
    const float* b1  = (const float*)d_in[3];
    const float* W1r = (const float*)d_in[4];
    const float* W2l = (const float*)d_in[5];
    const float* b2  = (const float*)d_in[6];
    const float* W2r = (const float*)d_in[7];
    float* out = (float*)d_out;

    const int E = in_sizes[1] / 2;
    const int* src = ei;
    const int* dst = ei + E;

    // ---- workspace layout (all 16B aligned) ----
    char* w = (char*)d_ws;
    int* cursor  = (int*)w;             w += 10016 * sizeof(int);
    int* bucket  = (int*)w;             w += (long long)N_NODES * BUCKET * sizeof(int);
    unsigned short* xb    = (unsigned short*)w; w += (long long)N_NODES * F_IN * 2;
    unsigned short* agg1b = (unsigned short*)w; w += (long long)N_NODES * F_IN * 2;
    unsigned short* W1T   = (unsigned short*)w; w += 512 * 512 * 2;
    unsigned short* W2T   = (unsigned short*)w; w += 256 * 512 * 2;
    unsigned short* h     = (unsigned short*)w; w += (long long)N_NODES * HID * 2;
    unsigned short* p     = (unsigned short*)w; w += (long long)N_NODES * C_OUT * 2;

    // ---- prep (convert/transpose/zero-cursor) + bucket fill ----
    prep_kernel<<<2894, 256, 0, stream>>>((const float4*)x, (uint2*)xb,
                                          W1l, W1r, W2l, W2r, W1T, W2T, (int4*)cursor);
    fill_kernel<<<(E + 255) / 256, 256, 0, stream>>>(src, dst, cursor, bucket, E);

    const int agg_blocks = (N_NODES * 64 + 255) / 256;

    // ---- layer 1 ----
    gather_agg_256<<<agg_blocks, 256, 0, stream>>>(xb, cursor, bucket, agg1b, N_NODES);
    {
        dim3 grid((N_NODES + 127) / 128, HID / 64);
        mfma_gemm<0><<<grid, 256, 0, stream>>>(agg1b, F_IN, xb, F_IN, W1T, b1,
                                               (void*)h, (void*)nullptr, N_NODES, HID);
    }

    // ---- layer 2 (aggregation swapped past the linear) ----
    {
        dim3 grid((N_NODES + 127) / 128, 256 / 64);
        mfma_gemm<1><<<grid, 256, 0, stream>>>(h, HID, h, 0, W2T, b2,
                                               (void*)p, (void*)out, N_NODES, 256);
    }
    gather_acc_128<<<agg_blocks, 256, 0, stream>>>(p, cursor, bucket, out, N_NODES);
}